// Round 5
// baseline (1025.507 us; speedup 1.0000x reference)
//
#include <hip/hip_runtime.h>
#include <hip/hip_bf16.h>

// EdgeConv block: B=8 clouds, N=4096 pts, K=20 nn, C_IN=64, C_OUT=128.
// Pipeline: k_prep (x -> bf16 hi/lo planes) -> k_sq -> k_wt
//   -> k_knn (MFMA split-bf16 distances; stash + sorted shift-insert top-20;
//             4-way early-exit merge -> 24; exact fp32 recheck -> top-20 set)
//   -> k_res (residual x@Wres+bres via MFMA, pre-fills out)
//   -> k_edge (gather + MFMA MLP1 + LN + MFMA MLP2 + LN + max, adds into out)

#define NB 8
#define NPTS 4096
#define KNN 20
#define CIN 64
#define COUT 128
#define NTOT (NB * NPTS)       // 32768
#define NEDGE (NTOT * KNN)     // 655360
#define LDA 136                // bf16 row stride (128 + 8 pad) -> 272 B

typedef short bf16x8 __attribute__((ext_vector_type(8)));
typedef float f32x4 __attribute__((ext_vector_type(4)));

__device__ __forceinline__ unsigned short f2bf(float f) {
    union { float f; unsigned u; } v; v.f = f;
    unsigned r = v.u + 0x7FFFu + ((v.u >> 16) & 1u);   // RTNE
    return (unsigned short)(r >> 16);
}
__device__ __forceinline__ float bf2f(unsigned short s) {
    union { unsigned u; float f; } v; v.u = ((unsigned)s) << 16;
    return v.f;
}

// ---------------- x -> bf16 hi/lo planes ----------------
__global__ __launch_bounds__(256) void k_prep(const float* __restrict__ x,
                                              unsigned short* __restrict__ xhi,
                                              unsigned short* __restrict__ xlo) {
    int id = blockIdx.x * 2048 + threadIdx.x * 8;
    float4 v0 = *(const float4*)(x + id);
    float4 v1 = *(const float4*)(x + id + 4);
    float vs[8] = {v0.x, v0.y, v0.z, v0.w, v1.x, v1.y, v1.z, v1.w};
    unsigned short h[8], l[8];
#pragma unroll
    for (int i = 0; i < 8; ++i) {
        h[i] = f2bf(vs[i]);
        l[i] = f2bf(vs[i] - bf2f(h[i]));
    }
    uint4 hp, lp;
    hp.x = h[0] | ((unsigned)h[1] << 16); hp.y = h[2] | ((unsigned)h[3] << 16);
    hp.z = h[4] | ((unsigned)h[5] << 16); hp.w = h[6] | ((unsigned)h[7] << 16);
    lp.x = l[0] | ((unsigned)l[1] << 16); lp.y = l[2] | ((unsigned)l[3] << 16);
    lp.z = l[4] | ((unsigned)l[5] << 16); lp.w = l[6] | ((unsigned)l[7] << 16);
    *(uint4*)(xhi + id) = hp;
    *(uint4*)(xlo + id) = lp;
}

// ---------------- sq[n] = sum_c x[n][c]^2 ----------------
__global__ __launch_bounds__(256) void k_sq(const float* __restrict__ x, float* __restrict__ sq) {
    int t = threadIdx.x;
    int n = blockIdx.x * 4 + (t >> 6);
    int lane = t & 63;
    float v = x[n * 64 + lane];
    float s = v * v;
#pragma unroll
    for (int m = 32; m >= 1; m >>= 1) s += __shfl_xor(s, m);
    if (lane == 0) sq[n] = s;
}

// ---------------- transpose W1,W2,Wres -> bf16 [out][in] ----------------
__global__ __launch_bounds__(256) void k_wt(const float* __restrict__ W1, const float* __restrict__ W2,
                                            const float* __restrict__ Wres,
                                            unsigned short* __restrict__ w1t, unsigned short* __restrict__ w2t,
                                            unsigned short* __restrict__ wrt) {
    int id = blockIdx.x * 256 + threadIdx.x;   // 0..40959
    if (id < 16384) {
        int c = id >> 7, d = id & 127;
        w1t[d * 128 + c] = f2bf(W1[id]);
    } else if (id < 32768) {
        int i2 = id - 16384;
        int c = i2 >> 7, d = i2 & 127;
        w2t[d * 128 + c] = f2bf(W2[i2]);
    } else {
        int i3 = id - 32768;                   // Wres is [64][128]
        int c = i3 >> 7, d = i3 & 127;
        wrt[d * 64 + c] = f2bf(Wres[i3]);
    }
}

// ---------------- KNN via MFMA + stash/sorted-insert selection ----------------
// Block: 256 thr = 4 waves; wave wv owns queries n0 + wv*16 + (lane&15).
// Lane owns (query lr, candidate quarter kg): streams 1024 candidates.
// Hot path: sc < kmax -> push (score,idx) to per-lane LDS stash (stride 17, conflict-free).
// Compaction (when any lane cnt>8, + final): branchless ascending shift-insert into kd[20].
// Merge: 4 sorted lists early-exit -> top-24 approx; exact fp32 recheck -> top-20 set.
__global__ __launch_bounds__(256) void k_knn(const float* __restrict__ x,
                                             const unsigned short* __restrict__ xhi,
                                             const unsigned short* __restrict__ xlo,
                                             const float* __restrict__ sq,
                                             int* __restrict__ knn_idx) {
    int b  = blockIdx.x & 7;           // cloud -> XCD pinning
    int qb = blockIdx.x >> 3;          // 0..63
    int t  = threadIdx.x;
    int wv = t >> 6, lane = t & 63;
    int lr = lane & 15, kg = lane >> 4;
    int n0  = b * NPTS + qb * 64;
    int cb0 = b * NPTS;

    __shared__ union {
        unsigned short frag[8][512];   // MFMA A-fragments, pre-packed per-lane order
        float xq[64][68];              // exact-phase query cache
    } smA;
    __shared__ union {
        struct { float sd[256 * 17]; int si[256 * 17]; } s;   // stash (34816 B)
        struct { float md[64][81]; int mi[64][81]; } m;       // merge lists (41472 B)
    } smB;
    __shared__ float ce[64][24];
    __shared__ int   ci[64][24];

    // query B-fragments (col = lane&15, k-slice kg*8), hi/lo x 2 K-halves
    int qg = n0 + wv * 16 + lr;
    bf16x8 qhi0 = *(const bf16x8*)(xhi + (size_t)qg * 64 + kg * 8);
    bf16x8 qhi1 = *(const bf16x8*)(xhi + (size_t)qg * 64 + 32 + kg * 8);
    bf16x8 qlo0 = *(const bf16x8*)(xlo + (size_t)qg * 64 + kg * 8);
    bf16x8 qlo1 = *(const bf16x8*)(xlo + (size_t)qg * 64 + 32 + kg * 8);

    float kd[KNN]; int ki[KNN];
#pragma unroll
    for (int p = 0; p < KNN; ++p) { kd[p] = 3.4e38f; ki[p] = 0; }
    float kmax = 3.4e38f;
    int cnt = 0;

    // branchless ascending sorted insert (x >= kd[19] is a no-op)
    auto insert20 = [&](float xv, int xid) {
        bool c[KNN];
#pragma unroll
        for (int p = 0; p < KNN; ++p) c[p] = xv < kd[p];
#pragma unroll
        for (int p = KNN - 1; p >= 1; --p) {
            kd[p] = c[p - 1] ? kd[p - 1] : (c[p] ? xv : kd[p]);
            ki[p] = c[p - 1] ? ki[p - 1] : (c[p] ? xid : ki[p]);
        }
        kd[0] = c[0] ? xv : kd[0];
        ki[0] = c[0] ? xid : ki[0];
    };
    auto compact = [&]() {
        int e = 0;
        while (__any(e < cnt)) {
            bool act = e < cnt;
            float xv = act ? smB.s.sd[t * 17 + e] : 3.4e38f;
            int  xid = act ? smB.s.si[t * 17 + e] : 0;
            insert20(xv, xid);
            ++e;
        }
        kmax = kd[KNN - 1];
        cnt = 0;
    };

    // wave's staging role: frags f0=2wv (kh=0), f1=2wv+1 (kh=1); tile stt=wv>>1, plane wv&1
    int stt = wv >> 1;
    const unsigned short* plane = (wv & 1) ? xlo : xhi;
    int f0 = 2 * wv, f1 = 2 * wv + 1;

    // preload iter 0
    const unsigned short* s0p = plane + (size_t)(cb0 + stt * 16 + lr) * 64 + kg * 8;
    uint4 g0 = *(const uint4*)s0p;
    uint4 g1 = *(const uint4*)(s0p + 32);
    float4 sqa = *(const float4*)&sq[cb0 + kg * 4];
    float4 sqb = *(const float4*)&sq[cb0 + 16 + kg * 4];

#pragma unroll 1
    for (int it = 0; it < 128; ++it) {
        int cb = cb0 + it * 32;
        if (__any(cnt > 8)) compact();        // CAP=16, <=8 pushes/iter -> no overflow
        __syncthreads();                       // (A) everyone done reading frag
        *(uint4*)&smA.frag[f0][lane * 8] = g0;
        *(uint4*)&smA.frag[f1][lane * 8] = g1;
        float4 s0c = sqa, s1c = sqb;
        __syncthreads();                       // (B) frag visible
        if (it + 1 < 128) {
            const unsigned short* sp = plane + (size_t)(cb + 32 + stt * 16 + lr) * 64 + kg * 8;
            g0 = *(const uint4*)sp;
            g1 = *(const uint4*)(sp + 32);
            sqa = *(const float4*)&sq[cb + 32 + kg * 4];
            sqb = *(const float4*)&sq[cb + 48 + kg * 4];
        }

        bf16x8 A0 = *(const bf16x8*)&smA.frag[0][lane * 8];
        bf16x8 A1 = *(const bf16x8*)&smA.frag[1][lane * 8];
        bf16x8 A2 = *(const bf16x8*)&smA.frag[2][lane * 8];
        bf16x8 A3 = *(const bf16x8*)&smA.frag[3][lane * 8];
        bf16x8 A4 = *(const bf16x8*)&smA.frag[4][lane * 8];
        bf16x8 A5 = *(const bf16x8*)&smA.frag[5][lane * 8];
        bf16x8 A6 = *(const bf16x8*)&smA.frag[6][lane * 8];
        bf16x8 A7 = *(const bf16x8*)&smA.frag[7][lane * 8];

        f32x4 a00 = {-0.5f * s0c.x, -0.5f * s0c.y, -0.5f * s0c.z, -0.5f * s0c.w};
        f32x4 a01 = {0.f, 0.f, 0.f, 0.f};
        f32x4 a10 = {-0.5f * s1c.x, -0.5f * s1c.y, -0.5f * s1c.z, -0.5f * s1c.w};
        f32x4 a11 = {0.f, 0.f, 0.f, 0.f};
        a00 = __builtin_amdgcn_mfma_f32_16x16x32_bf16(A0, qhi0, a00, 0, 0, 0);
        a10 = __builtin_amdgcn_mfma_f32_16x16x32_bf16(A4, qhi0, a10, 0, 0, 0);
        a01 = __builtin_amdgcn_mfma_f32_16x16x32_bf16(A1, qhi1, a01, 0, 0, 0);
        a11 = __builtin_amdgcn_mfma_f32_16x16x32_bf16(A5, qhi1, a11, 0, 0, 0);
        a00 = __builtin_amdgcn_mfma_f32_16x16x32_bf16(A2, qhi0, a00, 0, 0, 0);
        a10 = __builtin_amdgcn_mfma_f32_16x16x32_bf16(A6, qhi0, a10, 0, 0, 0);
        a01 = __builtin_amdgcn_mfma_f32_16x16x32_bf16(A3, qhi1, a01, 0, 0, 0);
        a11 = __builtin_amdgcn_mfma_f32_16x16x32_bf16(A7, qhi1, a11, 0, 0, 0);
        a00 = __builtin_amdgcn_mfma_f32_16x16x32_bf16(A0, qlo0, a00, 0, 0, 0);
        a10 = __builtin_amdgcn_mfma_f32_16x16x32_bf16(A4, qlo0, a10, 0, 0, 0);
        a01 = __builtin_amdgcn_mfma_f32_16x16x32_bf16(A1, qlo1, a01, 0, 0, 0);
        a11 = __builtin_amdgcn_mfma_f32_16x16x32_bf16(A5, qlo1, a11, 0, 0, 0);

        // push candidates to stash (1 cmp hot; masked 2x b32 LDS write, stride-17 rows)
#pragma unroll
        for (int j = 0; j < 4; ++j) {
            float sc = -(a00[j] + a01[j]);
            int cand = cb + kg * 4 + j;
            bool ok = sc < kmax;
            if (ok) { smB.s.sd[t * 17 + cnt] = sc; smB.s.si[t * 17 + cnt] = cand; }
            cnt += ok ? 1 : 0;
        }
#pragma unroll
        for (int j = 0; j < 4; ++j) {
            float sc = -(a10[j] + a11[j]);
            int cand = cb + 16 + kg * 4 + j;
            bool ok = sc < kmax;
            if (ok) { smB.s.sd[t * 17 + cnt] = sc; smB.s.si[t * 17 + cnt] = cand; }
            cnt += ok ? 1 : 0;
        }
    }
    compact();         // final drain: kd/ki sorted ascending

    __syncthreads();   // stash dead; smB reused as md/mi
    {
        int ql = wv * 16 + lr;
#pragma unroll
        for (int p = 0; p < KNN; ++p) {
            smB.m.md[ql][kg * KNN + p] = kd[p];
            smB.m.mi[ql][kg * KNN + p] = ki[p];
        }
    }
    __syncthreads();

    // merge 4 sorted lists -> approx top-24 (t<64) || stage xq fp32 (t>=64)
    if (t < 64) {
        float kdm[24]; int kim[24];
#pragma unroll
        for (int s = 0; s < 24; ++s) { kdm[s] = 3.4e38f; kim[s] = 0; }
        float km = 3.4e38f;
        auto insert24 = [&](float xv, int xid) {
            bool c[24];
#pragma unroll
            for (int p = 0; p < 24; ++p) c[p] = xv < kdm[p];
#pragma unroll
            for (int p = 23; p >= 1; --p) {
                kdm[p] = c[p - 1] ? kdm[p - 1] : (c[p] ? xv : kdm[p]);
                kim[p] = c[p - 1] ? kim[p - 1] : (c[p] ? xid : kim[p]);
            }
            kdm[0] = c[0] ? xv : kdm[0];
            kim[0] = c[0] ? xid : kim[0];
        };
#pragma unroll 1
        for (int u = 0; u < 4; ++u) {
#pragma unroll 1
            for (int p = 0; p < KNN; ++p) {
                float d = smB.m.md[t][u * KNN + p];
                if (d >= km) break;            // list ascending -> rest can't qualify
                insert24(d, smB.m.mi[t][u * KNN + p]);
                km = kdm[23];
            }
        }
#pragma unroll
        for (int s = 0; s < 24; ++s) ci[t][s] = kim[s];
    } else {
        for (int idx = t - 64; idx < 1024; idx += 192) {
            int q = idx >> 4, dg = idx & 15;
            *(float4*)&smA.xq[q][dg * 4] = *(const float4*)(x + (size_t)(n0 + q) * 64 + dg * 4);
        }
    }
    __syncthreads();

    // exact fp32 recheck: 4 threads/query x 6 cands
    {
        int q = t >> 2, sl = (t & 3) * 6;
#pragma unroll 1
        for (int u = 0; u < 6; ++u) {
            int cidx = ci[q][sl + u];
            const float* xc = x + (size_t)cidx * 64;
            float dot = 0.f;
#pragma unroll
            for (int g = 0; g < 16; ++g) {
                float4 a = *(const float4*)&smA.xq[q][g * 4];
                float4 bb = *(const float4*)(xc + g * 4);
                dot += a.x * bb.x + a.y * bb.y + a.z * bb.z + a.w * bb.w;
            }
            ce[q][sl + u] = 0.5f * sq[cidx] - dot;
        }
    }
    __syncthreads();

    // exclude the 4 lexicographically-largest (score, then higher idx) -> exact top-20 set
    if (t < 64) {
        float ev[24]; int iv[24];
#pragma unroll
        for (int s = 0; s < 24; ++s) { ev[s] = ce[t][s]; iv[s] = ci[t][s]; }
        unsigned mask = 0;
#pragma unroll
        for (int pass = 0; pass < 4; ++pass) {
            float best = -3.4e38f; int bid = -1, bs = 0;
#pragma unroll
            for (int s = 0; s < 24; ++s) {
                bool free_ = ((mask >> s) & 1u) == 0u;
                bool gt = (ev[s] > best) || (ev[s] == best && iv[s] > bid);
                if (free_ && gt) { best = ev[s]; bid = iv[s]; bs = s; }
            }
            mask |= 1u << bs;
        }
        int* op = knn_idx + (size_t)(n0 + t) * KNN;
        int pos = 0;
#pragma unroll
        for (int s = 0; s < 24; ++s)
            if (((mask >> s) & 1u) == 0u) op[pos++] = iv[s];
    }
}

// ---------------- residual: out = x @ Wres + bres (MFMA) ----------------
__global__ __launch_bounds__(256) void k_res(const float* __restrict__ x,
                                             const unsigned short* __restrict__ wrt,
                                             const float* __restrict__ bres,
                                             float* __restrict__ out) {
    int t = threadIdx.x;
    int wv = t >> 6, lane = t & 63;
    int lr = lane & 15, kg = lane >> 4;
    int n0 = blockIdx.x * 64 + wv * 16;

    const float* xp = x + (size_t)(n0 + lr) * 64;
    bf16x8 af0, af1;
    {
        union { unsigned short u[8]; bf16x8 v; } cv;
        float4 u0 = *(const float4*)(xp + kg * 8);
        float4 u1 = *(const float4*)(xp + kg * 8 + 4);
        cv.u[0] = f2bf(u0.x); cv.u[1] = f2bf(u0.y); cv.u[2] = f2bf(u0.z); cv.u[3] = f2bf(u0.w);
        cv.u[4] = f2bf(u1.x); cv.u[5] = f2bf(u1.y); cv.u[6] = f2bf(u1.z); cv.u[7] = f2bf(u1.w);
        af0 = cv.v;
        float4 w0 = *(const float4*)(xp + 32 + kg * 8);
        float4 w1 = *(const float4*)(xp + 32 + kg * 8 + 4);
        cv.u[0] = f2bf(w0.x); cv.u[1] = f2bf(w0.y); cv.u[2] = f2bf(w0.z); cv.u[3] = f2bf(w0.w);
        cv.u[4] = f2bf(w1.x); cv.u[5] = f2bf(w1.y); cv.u[6] = f2bf(w1.z); cv.u[7] = f2bf(w1.w);
        af1 = cv.v;
    }
    f32x4 acc[8];
#pragma unroll
    for (int nt = 0; nt < 8; ++nt) {
        float bv = bres[nt * 16 + lr];
        acc[nt] = (f32x4){bv, bv, bv, bv};
    }
#pragma unroll
    for (int nt = 0; nt < 8; ++nt) {
        bf16x8 b0 = *(const bf16x8*)(wrt + (size_t)(nt * 16 + lr) * 64 + kg * 8);
        bf16x8 b1 = *(const bf16x8*)(wrt + (size_t)(nt * 16 + lr) * 64 + 32 + kg * 8);
        acc[nt] = __builtin_amdgcn_mfma_f32_16x16x32_bf16(af0, b0, acc[nt], 0, 0, 0);
        acc[nt] = __builtin_amdgcn_mfma_f32_16x16x32_bf16(af1, b1, acc[nt], 0, 0, 0);
    }
    // C layout: col = nt*16+lr, row (point) = kg*4+j
#pragma unroll
    for (int nt = 0; nt < 8; ++nt)
#pragma unroll
        for (int j = 0; j < 4; ++j)
            out[(size_t)(n0 + kg * 4 + j) * 128 + nt * 16 + lr] = acc[nt][j];
}

// ---------------- fused edge MLP ----------------
__device__ __forceinline__ void gemm_tile(const unsigned short* A, const unsigned short* Bw,
                                          int wv, int lane, f32x4 acc[2][8]) {
    int lr = lane & 15, kg = lane >> 4;
#pragma unroll
    for (int ks = 0; ks < 4; ++ks) {
        int ko = ks * 32 + kg * 8;
        bf16x8 a0 = *(const bf16x8*)(A + (size_t)(wv * 32 + lr) * LDA + ko);
        bf16x8 a1 = *(const bf16x8*)(A + (size_t)(wv * 32 + 16 + lr) * LDA + ko);
#pragma unroll
        for (int nt = 0; nt < 8; ++nt) {
            bf16x8 bf = *(const bf16x8*)(Bw + (size_t)(nt * 16 + lr) * LDA + ko);
            acc[0][nt] = __builtin_amdgcn_mfma_f32_16x16x32_bf16(a0, bf, acc[0][nt], 0, 0, 0);
            acc[1][nt] = __builtin_amdgcn_mfma_f32_16x16x32_bf16(a1, bf, acc[1][nt], 0, 0, 0);
        }
    }
}

__device__ __forceinline__ void ln_relu_store(f32x4 acc[2][8], unsigned short* A, int wv, int lane,
                                              const float* __restrict__ bias, const float* __restrict__ g,
                                              const float* __restrict__ be) {
    int lc = lane & 15, kg = lane >> 4;
    float bv[8], gv[8], bev[8];
#pragma unroll
    for (int nt = 0; nt < 8; ++nt) {
        bv[nt]  = bias[nt * 16 + lc];
        gv[nt]  = g[nt * 16 + lc];
        bev[nt] = be[nt * 16 + lc];
    }
#pragma unroll
    for (int mt = 0; mt < 2; ++mt) {
#pragma unroll
        for (int j = 0; j < 4; ++j) {
            float v[8]; float s = 0.f, ss = 0.f;
#pragma unroll
            for (int nt = 0; nt < 8; ++nt) {
                v[nt] = acc[mt][nt][j] + bv[nt];
                s += v[nt]; ss += v[nt] * v[nt];
            }
#pragma unroll
            for (int m = 1; m < 16; m <<= 1) { s += __shfl_xor(s, m); ss += __shfl_xor(ss, m); }
            float mean = s * 0.0078125f;
            float var  = ss * 0.0078125f - mean * mean;
            float rstd = rsqrtf(fmaxf(var, 0.f) + 1e-5f);
            int row = wv * 32 + mt * 16 + kg * 4 + j;
#pragma unroll
            for (int nt = 0; nt < 8; ++nt) {
                float h = (v[nt] - mean) * rstd * gv[nt] + bev[nt];
                h = fmaxf(h, 0.f);
                A[(size_t)row * LDA + nt * 16 + lc] = f2bf(h);
            }
        }
    }
}

__global__ __launch_bounds__(320) void k_edge(const float* __restrict__ x, const int* __restrict__ knn_idx,
                                              const unsigned short* __restrict__ w1t, const unsigned short* __restrict__ w2t,
                                              const float* __restrict__ b1, const float* __restrict__ g1, const float* __restrict__ be1,
                                              const float* __restrict__ b2, const float* __restrict__ g2, const float* __restrict__ be2,
                                              float* __restrict__ out) {
    __shared__ unsigned short A[160 * LDA];
    __shared__ unsigned short Bw[128 * LDA];
    int t = threadIdx.x;
    int blk = blockIdx.x;

    {
        int r = t >> 1, half = t & 1;
        int eg = blk * 160 + r;
        int n = eg / 20;
        int j = knn_idx[eg];
        const float* xi = x + (size_t)n * 64;
        if (half == 0) {
#pragma unroll
            for (int i = 0; i < 16; ++i) {
                float4 v = *(const float4*)(xi + i * 4);
                ushort4 pk; pk.x = f2bf(v.x); pk.y = f2bf(v.y); pk.z = f2bf(v.z); pk.w = f2bf(v.w);
                *(ushort4*)&A[(size_t)r * LDA + i * 4] = pk;
            }
        } else {
            const float* xj = x + (size_t)j * 64;
#pragma unroll
            for (int i = 0; i < 16; ++i) {
                float4 vi = *(const float4*)(xi + i * 4);
                float4 vj = *(const float4*)(xj + i * 4);
                ushort4 pk; pk.x = f2bf(vj.x - vi.x); pk.y = f2bf(vj.y - vi.y);
                pk.z = f2bf(vj.z - vi.z); pk.w = f2bf(vj.w - vi.w);
                *(ushort4*)&A[(size_t)r * LDA + 64 + i * 4] = pk;
            }
        }
    }
    for (int id = t; id < 2048; id += 320) {
        int row = id >> 4, ch = id & 15;
        *(uint4*)&Bw[(size_t)row * LDA + ch * 8] = *(const uint4*)(w1t + (size_t)row * 128 + ch * 8);
    }
    __syncthreads();

    int wv = t >> 6, lane = t & 63;
    f32x4 acc[2][8];
#pragma unroll
    for (int i = 0; i < 2; ++i)
#pragma unroll
        for (int j = 0; j < 8; ++j) acc[i][j] = (f32x4){0.f, 0.f, 0.f, 0.f};
    gemm_tile(A, Bw, wv, lane, acc);
    ln_relu_store(acc, A, wv, lane, b1, g1, be1);
    __syncthreads();
    for (int id = t; id < 2048; id += 320) {
        int row = id >> 4, ch = id & 15;
        *(uint4*)&Bw[(size_t)row * LDA + ch * 8] = *(const uint4*)(w2t + (size_t)row * 128 + ch * 8);
    }
    __syncthreads();

    f32x4 acc2[2][8];
#pragma unroll
    for (int i = 0; i < 2; ++i)
#pragma unroll
        for (int j = 0; j < 8; ++j) acc2[i][j] = (f32x4){0.f, 0.f, 0.f, 0.f};
    gemm_tile(A, Bw, wv, lane, acc2);
    ln_relu_store(acc2, A, wv, lane, b2, g2, be2);
    __syncthreads();

    // max over K, add into pre-filled residual
    for (int i = t; i < 1024; i += 320) {
        int p = i >> 7, c = i & 127;
        float mx = 0.f;
#pragma unroll
        for (int r = 0; r < 20; ++r)
            mx = fmaxf(mx, bf2f(A[(size_t)(p * 20 + r) * LDA + c]));
        int n = blk * 8 + p;
        out[(size_t)n * 128 + c] += mx;
    }
}

// ---------------- launcher ----------------
extern "C" void kernel_launch(void* const* d_in, const int* in_sizes, int n_in,
                              void* d_out, int out_size, void* d_ws, size_t ws_size,
                              hipStream_t stream) {
    const float* x    = (const float*)d_in[0];
    const float* W1   = (const float*)d_in[2];
    const float* b1   = (const float*)d_in[3];
    const float* g1   = (const float*)d_in[4];
    const float* be1  = (const float*)d_in[5];
    const float* W2   = (const float*)d_in[6];
    const float* b2   = (const float*)d_in[7];
    const float* g2   = (const float*)d_in[8];
    const float* be2  = (const float*)d_in[9];
    const float* Wres = (const float*)d_in[10];
    const float* bres = (const float*)d_in[11];
    float* out = (float*)d_out;

    char* ws = (char*)d_ws;
    float* sq            = (float*)(ws);                     // 131072 B
    unsigned short* w1t  = (unsigned short*)(ws + 131072);   // 32768 B
    unsigned short* w2t  = (unsigned short*)(ws + 163840);   // 32768 B
    int* knn_idx         = (int*)(ws + 196608);              // 2621440 B
    unsigned short* wrt  = (unsigned short*)(ws + 2818048);  // 16384 B  (total ~2.9 MB)

    // bf16 hi/lo planes staged inside d_out; consumed by k_knn, then overwritten by k_res
    unsigned short* xhi = (unsigned short*)d_out;                       // 4 MB
    unsigned short* xlo = (unsigned short*)((char*)d_out + 4194304);    // 4 MB

    k_prep <<<dim3(1024),     dim3(256), 0, stream>>>(x, xhi, xlo);
    k_sq   <<<dim3(NTOT / 4), dim3(256), 0, stream>>>(x, sq);
    k_wt   <<<dim3(160),      dim3(256), 0, stream>>>(W1, W2, Wres, w1t, w2t, wrt);
    k_knn  <<<dim3(NB * 64),  dim3(256), 0, stream>>>(x, xhi, xlo, sq, knn_idx);
    k_res  <<<dim3(NTOT / 64),dim3(256), 0, stream>>>(x, wrt, bres, out);
    k_edge <<<dim3(NEDGE / 160), dim3(320), 0, stream>>>(x, knn_idx, w1t, w2t,
                                                         b1, g1, be1, b2, g2, be2, out);
}

// Round 6
// 729.451 us; speedup vs baseline: 1.4059x; 1.4059x over previous
//
#include <hip/hip_runtime.h>
#include <hip/hip_bf16.h>

// EdgeConv block: B=8 clouds, N=4096 pts, K=20 nn, C_IN=64, C_OUT=128.
// Pipeline: k_prep (x -> bf16 hi/lo planes) -> k_sq -> k_wt
//   -> k_knn two-pass: P1 MFMA distances + values-only med3 top-20 -> tau_q;
//                      P2 re-stream, collect survivors (sc <= tau+eps) -> exact fp32 recheck -> top-20 set
//   -> k_res (residual x@Wres+bres via MFMA, pre-fills out)
//   -> k_edge (gather + MFMA MLP1 + LN + MFMA MLP2 + LN + max, adds into out)

#define NB 8
#define NPTS 4096
#define KNN 20
#define CIN 64
#define COUT 128
#define NTOT (NB * NPTS)       // 32768
#define NEDGE (NTOT * KNN)     // 655360
#define LDA 136                // bf16 row stride (128 + 8 pad) -> 272 B
#define KEPS 0.02f             // >> 2x split-bf16 score error (~1e-3)

typedef short bf16x8 __attribute__((ext_vector_type(8)));
typedef float f32x4 __attribute__((ext_vector_type(4)));

__device__ __forceinline__ unsigned short f2bf(float f) {
    union { float f; unsigned u; } v; v.f = f;
    unsigned r = v.u + 0x7FFFu + ((v.u >> 16) & 1u);   // RTNE
    return (unsigned short)(r >> 16);
}
__device__ __forceinline__ float bf2f(unsigned short s) {
    union { unsigned u; float f; } v; v.u = ((unsigned)s) << 16;
    return v.f;
}

// ---------------- x -> bf16 hi/lo planes ----------------
__global__ __launch_bounds__(256) void k_prep(const float* __restrict__ x,
                                              unsigned short* __restrict__ xhi,
                                              unsigned short* __restrict__ xlo) {
    int id = blockIdx.x * 2048 + threadIdx.x * 8;
    float4 v0 = *(const float4*)(x + id);
    float4 v1 = *(const float4*)(x + id + 4);
    float vs[8] = {v0.x, v0.y, v0.z, v0.w, v1.x, v1.y, v1.z, v1.w};
    unsigned short h[8], l[8];
#pragma unroll
    for (int i = 0; i < 8; ++i) {
        h[i] = f2bf(vs[i]);
        l[i] = f2bf(vs[i] - bf2f(h[i]));
    }
    uint4 hp, lp;
    hp.x = h[0] | ((unsigned)h[1] << 16); hp.y = h[2] | ((unsigned)h[3] << 16);
    hp.z = h[4] | ((unsigned)h[5] << 16); hp.w = h[6] | ((unsigned)h[7] << 16);
    lp.x = l[0] | ((unsigned)l[1] << 16); lp.y = l[2] | ((unsigned)l[3] << 16);
    lp.z = l[4] | ((unsigned)l[5] << 16); lp.w = l[6] | ((unsigned)l[7] << 16);
    *(uint4*)(xhi + id) = hp;
    *(uint4*)(xlo + id) = lp;
}

// ---------------- sq[n] = sum_c x[n][c]^2 ----------------
__global__ __launch_bounds__(256) void k_sq(const float* __restrict__ x, float* __restrict__ sq) {
    int t = threadIdx.x;
    int n = blockIdx.x * 4 + (t >> 6);
    int lane = t & 63;
    float v = x[n * 64 + lane];
    float s = v * v;
#pragma unroll
    for (int m = 32; m >= 1; m >>= 1) s += __shfl_xor(s, m);
    if (lane == 0) sq[n] = s;
}

// ---------------- transpose W1,W2,Wres -> bf16 [out][in] ----------------
__global__ __launch_bounds__(256) void k_wt(const float* __restrict__ W1, const float* __restrict__ W2,
                                            const float* __restrict__ Wres,
                                            unsigned short* __restrict__ w1t, unsigned short* __restrict__ w2t,
                                            unsigned short* __restrict__ wrt) {
    int id = blockIdx.x * 256 + threadIdx.x;   // 0..40959
    if (id < 16384) {
        int c = id >> 7, d = id & 127;
        w1t[d * 128 + c] = f2bf(W1[id]);
    } else if (id < 32768) {
        int i2 = id - 16384;
        int c = i2 >> 7, d = i2 & 127;
        w2t[d * 128 + c] = f2bf(W2[i2]);
    } else {
        int i3 = id - 32768;                   // Wres is [64][128]
        int c = i3 >> 7, d = i3 & 127;
        wrt[d * 64 + c] = f2bf(Wres[i3]);
    }
}

// ---------------- KNN via MFMA, two-pass ----------------
// Block: 256 thr = 4 waves; wave wv owns queries n0 + wv*16 + (lane&15).
// Lane owns (query lr, candidate quarter kg): streams 1024 of 4096 candidates.
// Pass 1: per-candidate UNCONDITIONAL values-only sorted-20 insert:
//         kd[p] = min(max(x, kd[p-1]), kd[p])  (med3; 2 ops/slot, depth 2).
//         Then 4-way merge of sorted lists -> exact approx-metric tau_q.
// Pass 2: identical (bit-deterministic) MFMA stream; sc <= tau_q+eps -> push idx
//         to per-query LDS list (LDS atomic; ~20 survivors/query).
// Exact fp32 recheck of survivors -> true top-20 set by (score, idx).
__global__ __launch_bounds__(256, 3) void k_knn(const float* __restrict__ x,
                                                const unsigned short* __restrict__ xhi,
                                                const unsigned short* __restrict__ xlo,
                                                const float* __restrict__ sq,
                                                int* __restrict__ knn_idx) {
    int b  = blockIdx.x & 7;           // cloud -> XCD pinning
    int qb = blockIdx.x >> 3;          // 0..63
    int t  = threadIdx.x;
    int wv = t >> 6, lane = t & 63;
    int lr = lane & 15, kg = lane >> 4;
    int n0  = b * NPTS + qb * 64;
    int cb0 = b * NPTS;

    __shared__ union {
        unsigned short frag[8][512];   // MFMA A-fragments (8192 B), per-lane packed
        float ce[64][32];              // exact recheck scores (after pass 2)
    } F;
    __shared__ union {
        float md[64][81];              // per-lane sorted top-20 values (merge phase)
        float xq[64][68];              // fp32 query cache (recheck phase)
    } U;
    __shared__ float tau[64];
    __shared__ int   surv[64][32];
    __shared__ int   qcnt[64];

    // query B-fragments (col = lane&15, k-slice kg*8), hi/lo x 2 K-halves
    int qg = n0 + wv * 16 + lr;
    bf16x8 qhi0 = *(const bf16x8*)(xhi + (size_t)qg * 64 + kg * 8);
    bf16x8 qhi1 = *(const bf16x8*)(xhi + (size_t)qg * 64 + 32 + kg * 8);
    bf16x8 qlo0 = *(const bf16x8*)(xlo + (size_t)qg * 64 + kg * 8);
    bf16x8 qlo1 = *(const bf16x8*)(xlo + (size_t)qg * 64 + 32 + kg * 8);

    // wave's staging role: frags f0=2wv (K-half 0), f1=2wv+1 (K-half 1);
    // candidate sub-tile stt=wv>>1, plane hi (wv even) / lo (wv odd)
    int stt = wv >> 1;
    const unsigned short* plane = (wv & 1) ? xlo : xhi;
    int f0 = 2 * wv, f1 = 2 * wv + 1;

    float kd[KNN];
#pragma unroll
    for (int p = 0; p < KNN; ++p) kd[p] = 3.4e38f;
    int myq = wv * 16 + lr;
    float tq = 0.f;

    for (int pass = 0; pass < 2; ++pass) {
        // preload iter 0
        const unsigned short* s0p = plane + (size_t)(cb0 + stt * 16 + lr) * 64 + kg * 8;
        uint4 g0 = *(const uint4*)s0p;
        uint4 g1 = *(const uint4*)(s0p + 32);
        float4 sqa = *(const float4*)&sq[cb0 + kg * 4];
        float4 sqb = *(const float4*)&sq[cb0 + 16 + kg * 4];

#pragma unroll 1
        for (int it = 0; it < 128; ++it) {
            int cb = cb0 + it * 32;
            __syncthreads();                       // (A) everyone done reading frag
            *(uint4*)&F.frag[f0][lane * 8] = g0;
            *(uint4*)&F.frag[f1][lane * 8] = g1;
            float4 s0c = sqa, s1c = sqb;
            __syncthreads();                       // (B) frag visible
            if (it + 1 < 128) {
                const unsigned short* sp = plane + (size_t)(cb + 32 + stt * 16 + lr) * 64 + kg * 8;
                g0 = *(const uint4*)sp;
                g1 = *(const uint4*)(sp + 32);
                sqa = *(const float4*)&sq[cb + 32 + kg * 4];
                sqb = *(const float4*)&sq[cb + 48 + kg * 4];
            }

            bf16x8 A0 = *(const bf16x8*)&F.frag[0][lane * 8];
            bf16x8 A1 = *(const bf16x8*)&F.frag[1][lane * 8];
            bf16x8 A2 = *(const bf16x8*)&F.frag[2][lane * 8];
            bf16x8 A3 = *(const bf16x8*)&F.frag[3][lane * 8];
            bf16x8 A4 = *(const bf16x8*)&F.frag[4][lane * 8];
            bf16x8 A5 = *(const bf16x8*)&F.frag[5][lane * 8];
            bf16x8 A6 = *(const bf16x8*)&F.frag[6][lane * 8];
            bf16x8 A7 = *(const bf16x8*)&F.frag[7][lane * 8];

            f32x4 a00 = {-0.5f * s0c.x, -0.5f * s0c.y, -0.5f * s0c.z, -0.5f * s0c.w};
            f32x4 a01 = {0.f, 0.f, 0.f, 0.f};
            f32x4 a10 = {-0.5f * s1c.x, -0.5f * s1c.y, -0.5f * s1c.z, -0.5f * s1c.w};
            f32x4 a11 = {0.f, 0.f, 0.f, 0.f};
            a00 = __builtin_amdgcn_mfma_f32_16x16x32_bf16(A0, qhi0, a00, 0, 0, 0);
            a10 = __builtin_amdgcn_mfma_f32_16x16x32_bf16(A4, qhi0, a10, 0, 0, 0);
            a01 = __builtin_amdgcn_mfma_f32_16x16x32_bf16(A1, qhi1, a01, 0, 0, 0);
            a11 = __builtin_amdgcn_mfma_f32_16x16x32_bf16(A5, qhi1, a11, 0, 0, 0);
            a00 = __builtin_amdgcn_mfma_f32_16x16x32_bf16(A2, qhi0, a00, 0, 0, 0);
            a10 = __builtin_amdgcn_mfma_f32_16x16x32_bf16(A6, qhi0, a10, 0, 0, 0);
            a01 = __builtin_amdgcn_mfma_f32_16x16x32_bf16(A3, qhi1, a01, 0, 0, 0);
            a11 = __builtin_amdgcn_mfma_f32_16x16x32_bf16(A7, qhi1, a11, 0, 0, 0);
            a00 = __builtin_amdgcn_mfma_f32_16x16x32_bf16(A0, qlo0, a00, 0, 0, 0);
            a10 = __builtin_amdgcn_mfma_f32_16x16x32_bf16(A4, qlo0, a10, 0, 0, 0);
            a01 = __builtin_amdgcn_mfma_f32_16x16x32_bf16(A1, qlo1, a01, 0, 0, 0);
            a11 = __builtin_amdgcn_mfma_f32_16x16x32_bf16(A5, qlo1, a11, 0, 0, 0);

            float sc[8];
#pragma unroll
            for (int j = 0; j < 4; ++j) sc[j] = -(a00[j] + a01[j]);
#pragma unroll
            for (int j = 0; j < 4; ++j) sc[4 + j] = -(a10[j] + a11[j]);

            if (pass == 0) {
                // unconditional med3 sorted insert, values only (39 ops, depth 2)
#pragma unroll
                for (int j = 0; j < 8; ++j) {
                    float xv = sc[j];
#pragma unroll
                    for (int p = KNN - 1; p >= 1; --p)
                        kd[p] = fminf(fmaxf(xv, kd[p - 1]), kd[p]);
                    kd[0] = fminf(kd[0], xv);
                }
            } else {
                // survivor push (rare at wave level)
#pragma unroll
                for (int j = 0; j < 8; ++j) {
                    int cand = cb + ((j >> 2) << 4) + kg * 4 + (j & 3);
                    if (sc[j] <= tq) {
                        int p = atomicAdd(&qcnt[myq], 1);
                        if (p < 32) surv[myq][p] = cand;
                    }
                }
            }
        }

        if (pass == 0) {
            __syncthreads();   // frag reads done; start md phase
#pragma unroll
            for (int p = 0; p < KNN; ++p) U.md[myq][kg * KNN + p] = kd[p];
            __syncthreads();
            if (t < 64) {
                // 4-way merge of sorted ascending lists: tau = 20th smallest of 80
                int h0 = 0, h1 = 0, h2 = 0, h3 = 0;
                float tauv = 3.4e38f;
#pragma unroll 1
                for (int o = 0; o < KNN; ++o) {
                    float d0 = (h0 < KNN) ? U.md[t][0 * KNN + h0] : 3.5e38f;
                    float d1 = (h1 < KNN) ? U.md[t][1 * KNN + h1] : 3.5e38f;
                    float d2 = (h2 < KNN) ? U.md[t][2 * KNN + h2] : 3.5e38f;
                    float d3 = (h3 < KNN) ? U.md[t][3 * KNN + h3] : 3.5e38f;
                    float mm = fminf(fminf(d0, d1), fminf(d2, d3));
                    tauv = mm;
                    if (mm == d0) ++h0;
                    else if (mm == d1) ++h1;
                    else if (mm == d2) ++h2;
                    else ++h3;
                }
                tau[t] = tauv;
                qcnt[t] = 0;
            }
            __syncthreads();
            // stage fp32 query cache (md dead)
            for (int idx = t; idx < 1024; idx += 256) {
                int q = idx >> 4, dg = idx & 15;
                *(float4*)&U.xq[q][dg * 4] = *(const float4*)(x + (size_t)(n0 + q) * 64 + dg * 4);
            }
            __syncthreads();
            tq = tau[myq] + KEPS;
        }
    }

    __syncthreads();   // pass-2 frag reads + pushes done; F reused as ce

    // exact fp32 recheck: 4 threads/query over its m survivors
    {
        int q = t >> 2, sl = t & 3;
        int m = min(qcnt[q], 32);
#pragma unroll 1
        for (int p = sl; p < m; p += 4) {
            int cidx = surv[q][p];
            const float* xc = x + (size_t)cidx * 64;
            float dot = 0.f;
#pragma unroll
            for (int g = 0; g < 16; ++g) {
                float4 a = *(const float4*)&U.xq[q][g * 4];
                float4 bb = *(const float4*)(xc + g * 4);
                dot += a.x * bb.x + a.y * bb.y + a.z * bb.z + a.w * bb.w;
            }
            F.ce[q][p] = 0.5f * sq[cidx] - dot;
        }
    }
    __syncthreads();

    // final: 20 smallest of m by (exact score, lower idx)
    if (t < 64) {
        int m = min(qcnt[t], 32);
        float kd2[KNN]; int ki2[KNN];
#pragma unroll
        for (int p = 0; p < KNN; ++p) { kd2[p] = 3.4e38f; ki2[p] = 0x7fffffff; }
#pragma unroll 1
        for (int e = 0; e < m; ++e) {
            float xv = F.ce[t][e]; int xid = surv[t][e];
            bool c[KNN];
#pragma unroll
            for (int p = 0; p < KNN; ++p)
                c[p] = (xv < kd2[p]) || (xv == kd2[p] && xid < ki2[p]);
#pragma unroll
            for (int p = KNN - 1; p >= 1; --p) {
                kd2[p] = c[p - 1] ? kd2[p - 1] : (c[p] ? xv : kd2[p]);
                ki2[p] = c[p - 1] ? ki2[p - 1] : (c[p] ? xid : ki2[p]);
            }
            kd2[0] = c[0] ? xv : kd2[0];
            ki2[0] = c[0] ? xid : ki2[0];
        }
        int* op = knn_idx + (size_t)(n0 + t) * KNN;
#pragma unroll
        for (int p = 0; p < KNN; ++p) op[p] = ki2[p];
    }
}

// ---------------- residual: out = x @ Wres + bres (MFMA) ----------------
__global__ __launch_bounds__(256) void k_res(const float* __restrict__ x,
                                             const unsigned short* __restrict__ wrt,
                                             const float* __restrict__ bres,
                                             float* __restrict__ out) {
    int t = threadIdx.x;
    int wv = t >> 6, lane = t & 63;
    int lr = lane & 15, kg = lane >> 4;
    int n0 = blockIdx.x * 64 + wv * 16;

    const float* xp = x + (size_t)(n0 + lr) * 64;
    bf16x8 af0, af1;
    {
        union { unsigned short u[8]; bf16x8 v; } cv;
        float4 u0 = *(const float4*)(xp + kg * 8);
        float4 u1 = *(const float4*)(xp + kg * 8 + 4);
        cv.u[0] = f2bf(u0.x); cv.u[1] = f2bf(u0.y); cv.u[2] = f2bf(u0.z); cv.u[3] = f2bf(u0.w);
        cv.u[4] = f2bf(u1.x); cv.u[5] = f2bf(u1.y); cv.u[6] = f2bf(u1.z); cv.u[7] = f2bf(u1.w);
        af0 = cv.v;
        float4 w0 = *(const float4*)(xp + 32 + kg * 8);
        float4 w1 = *(const float4*)(xp + 32 + kg * 8 + 4);
        cv.u[0] = f2bf(w0.x); cv.u[1] = f2bf(w0.y); cv.u[2] = f2bf(w0.z); cv.u[3] = f2bf(w0.w);
        cv.u[4] = f2bf(w1.x); cv.u[5] = f2bf(w1.y); cv.u[6] = f2bf(w1.z); cv.u[7] = f2bf(w1.w);
        af1 = cv.v;
    }
    f32x4 acc[8];
#pragma unroll
    for (int nt = 0; nt < 8; ++nt) {
        float bv = bres[nt * 16 + lr];
        acc[nt] = (f32x4){bv, bv, bv, bv};
    }
#pragma unroll
    for (int nt = 0; nt < 8; ++nt) {
        bf16x8 b0 = *(const bf16x8*)(wrt + (size_t)(nt * 16 + lr) * 64 + kg * 8);
        bf16x8 b1 = *(const bf16x8*)(wrt + (size_t)(nt * 16 + lr) * 64 + 32 + kg * 8);
        acc[nt] = __builtin_amdgcn_mfma_f32_16x16x32_bf16(af0, b0, acc[nt], 0, 0, 0);
        acc[nt] = __builtin_amdgcn_mfma_f32_16x16x32_bf16(af1, b1, acc[nt], 0, 0, 0);
    }
#pragma unroll
    for (int nt = 0; nt < 8; ++nt)
#pragma unroll
        for (int j = 0; j < 4; ++j)
            out[(size_t)(n0 + kg * 4 + j) * 128 + nt * 16 + lr] = acc[nt][j];
}

// ---------------- fused edge MLP ----------------
__device__ __forceinline__ void gemm_tile(const unsigned short* A, const unsigned short* Bw,
                                          int wv, int lane, f32x4 acc[2][8]) {
    int lr = lane & 15, kg = lane >> 4;
#pragma unroll
    for (int ks = 0; ks < 4; ++ks) {
        int ko = ks * 32 + kg * 8;
        bf16x8 a0 = *(const bf16x8*)(A + (size_t)(wv * 32 + lr) * LDA + ko);
        bf16x8 a1 = *(const bf16x8*)(A + (size_t)(wv * 32 + 16 + lr) * LDA + ko);
#pragma unroll
        for (int nt = 0; nt < 8; ++nt) {
            bf16x8 bf = *(const bf16x8*)(Bw + (size_t)(nt * 16 + lr) * LDA + ko);
            acc[0][nt] = __builtin_amdgcn_mfma_f32_16x16x32_bf16(a0, bf, acc[0][nt], 0, 0, 0);
            acc[1][nt] = __builtin_amdgcn_mfma_f32_16x16x32_bf16(a1, bf, acc[1][nt], 0, 0, 0);
        }
    }
}

__device__ __forceinline__ void ln_relu_store(f32x4 acc[2][8], unsigned short* A, int wv, int lane,
                                              const float* __restrict__ bias, const float* __restrict__ g,
                                              const float* __restrict__ be) {
    int lc = lane & 15, kg = lane >> 4;
    float bv[8], gv[8], bev[8];
#pragma unroll
    for (int nt = 0; nt < 8; ++nt) {
        bv[nt]  = bias[nt * 16 + lc];
        gv[nt]  = g[nt * 16 + lc];
        bev[nt] = be[nt * 16 + lc];
    }
#pragma unroll
    for (int mt = 0; mt < 2; ++mt) {
#pragma unroll
        for (int j = 0; j < 4; ++j) {
            float v[8]; float s = 0.f, ss = 0.f;
#pragma unroll
            for (int nt = 0; nt < 8; ++nt) {
                v[nt] = acc[mt][nt][j] + bv[nt];
                s += v[nt]; ss += v[nt] * v[nt];
            }
#pragma unroll
            for (int m = 1; m < 16; m <<= 1) { s += __shfl_xor(s, m); ss += __shfl_xor(ss, m); }
            float mean = s * 0.0078125f;
            float var  = ss * 0.0078125f - mean * mean;
            float rstd = rsqrtf(fmaxf(var, 0.f) + 1e-5f);
            int row = wv * 32 + mt * 16 + kg * 4 + j;
#pragma unroll
            for (int nt = 0; nt < 8; ++nt) {
                float h = (v[nt] - mean) * rstd * gv[nt] + bev[nt];
                h = fmaxf(h, 0.f);
                A[(size_t)row * LDA + nt * 16 + lc] = f2bf(h);
            }
        }
    }
}

__global__ __launch_bounds__(320) void k_edge(const float* __restrict__ x, const int* __restrict__ knn_idx,
                                              const unsigned short* __restrict__ w1t, const unsigned short* __restrict__ w2t,
                                              const float* __restrict__ b1, const float* __restrict__ g1, const float* __restrict__ be1,
                                              const float* __restrict__ b2, const float* __restrict__ g2, const float* __restrict__ be2,
                                              float* __restrict__ out) {
    __shared__ unsigned short A[160 * LDA];
    __shared__ unsigned short Bw[128 * LDA];
    int t = threadIdx.x;
    int blk = blockIdx.x;

    {
        int r = t >> 1, half = t & 1;
        int eg = blk * 160 + r;
        int n = eg / 20;
        int j = knn_idx[eg];
        const float* xi = x + (size_t)n * 64;
        if (half == 0) {
#pragma unroll
            for (int i = 0; i < 16; ++i) {
                float4 v = *(const float4*)(xi + i * 4);
                ushort4 pk; pk.x = f2bf(v.x); pk.y = f2bf(v.y); pk.z = f2bf(v.z); pk.w = f2bf(v.w);
                *(ushort4*)&A[(size_t)r * LDA + i * 4] = pk;
            }
        } else {
            const float* xj = x + (size_t)j * 64;
#pragma unroll
            for (int i = 0; i < 16; ++i) {
                float4 vi = *(const float4*)(xi + i * 4);
                float4 vj = *(const float4*)(xj + i * 4);
                ushort4 pk; pk.x = f2bf(vj.x - vi.x); pk.y = f2bf(vj.y - vi.y);
                pk.z = f2bf(vj.z - vi.z); pk.w = f2bf(vj.w - vi.w);
                *(ushort4*)&A[(size_t)r * LDA + 64 + i * 4] = pk;
            }
        }
    }
    for (int id = t; id < 2048; id += 320) {
        int row = id >> 4, ch = id & 15;
        *(uint4*)&Bw[(size_t)row * LDA + ch * 8] = *(const uint4*)(w1t + (size_t)row * 128 + ch * 8);
    }
    __syncthreads();

    int wv = t >> 6, lane = t & 63;
    f32x4 acc[2][8];
#pragma unroll
    for (int i = 0; i < 2; ++i)
#pragma unroll
        for (int j = 0; j < 8; ++j) acc[i][j] = (f32x4){0.f, 0.f, 0.f, 0.f};
    gemm_tile(A, Bw, wv, lane, acc);
    ln_relu_store(acc, A, wv, lane, b1, g1, be1);
    __syncthreads();
    for (int id = t; id < 2048; id += 320) {
        int row = id >> 4, ch = id & 15;
        *(uint4*)&Bw[(size_t)row * LDA + ch * 8] = *(const uint4*)(w2t + (size_t)row * 128 + ch * 8);
    }
    __syncthreads();

    f32x4 acc2[2][8];
#pragma unroll
    for (int i = 0; i < 2; ++i)
#pragma unroll
        for (int j = 0; j < 8; ++j) acc2[i][j] = (f32x4){0.f, 0.f, 0.f, 0.f};
    gemm_tile(A, Bw, wv, lane, acc2);
    ln_relu_store(acc2, A, wv, lane, b2, g2, be2);
    __syncthreads();

    // max over K, add into pre-filled residual
    for (int i = t; i < 1024; i += 320) {
        int p = i >> 7, c = i & 127;
        float mx = 0.f;
#pragma unroll
        for (int r = 0; r < 20; ++r)
            mx = fmaxf(mx, bf2f(A[(size_t)(p * 20 + r) * LDA + c]));
        int n = blk * 8 + p;
        out[(size_t)n * 128 + c] += mx;
    }
}

// ---------------- launcher ----------------
extern "C" void kernel_launch(void* const* d_in, const int* in_sizes, int n_in,
                              void* d_out, int out_size, void* d_ws, size_t ws_size,
                              hipStream_t stream) {
    const float* x    = (const float*)d_in[0];
    const float* W1   = (const float*)d_in[2];
    const float* b1   = (const float*)d_in[3];
    const float* g1   = (const float*)d_in[4];
    const float* be1  = (const float*)d_in[5];
    const float* W2   = (const float*)d_in[6];
    const float* b2   = (const float*)d_in[7];
    const float* g2   = (const float*)d_in[8];
    const float* be2  = (const float*)d_in[9];
    const float* Wres = (const float*)d_in[10];
    const float* bres = (const float*)d_in[11];
    float* out = (float*)d_out;

    char* ws = (char*)d_ws;
    float* sq            = (float*)(ws);                     // 131072 B
    unsigned short* w1t  = (unsigned short*)(ws + 131072);   // 32768 B
    unsigned short* w2t  = (unsigned short*)(ws + 163840);   // 32768 B
    int* knn_idx         = (int*)(ws + 196608);              // 2621440 B
    unsigned short* wrt  = (unsigned short*)(ws + 2818048);  // 16384 B  (total ~2.9 MB)

    // bf16 hi/lo planes staged inside d_out; consumed by k_knn, then overwritten by k_res
    unsigned short* xhi = (unsigned short*)d_out;                       // 4 MB
    unsigned short* xlo = (unsigned short*)((char*)d_out + 4194304);    // 4 MB

    k_prep <<<dim3(1024),     dim3(256), 0, stream>>>(x, xhi, xlo);
    k_sq   <<<dim3(NTOT / 4), dim3(256), 0, stream>>>(x, sq);
    k_wt   <<<dim3(160),      dim3(256), 0, stream>>>(W1, W2, Wres, w1t, w2t, wrt);
    k_knn  <<<dim3(NB * 64),  dim3(256), 0, stream>>>(x, xhi, xlo, sq, knn_idx);
    k_res  <<<dim3(NTOT / 64),dim3(256), 0, stream>>>(x, wrt, bres, out);
    k_edge <<<dim3(NEDGE / 160), dim3(320), 0, stream>>>(x, knn_idx, w1t, w2t,
                                                         b1, g1, be1, b2, g2, be2, out);
}

// Round 7
// 567.139 us; speedup vs baseline: 1.8082x; 1.2862x over previous
//
#include <hip/hip_runtime.h>
#include <hip/hip_bf16.h>

// EdgeConv block: B=8 clouds, N=4096 pts, K=20 nn, C_IN=64, C_OUT=128.
// Pipeline: k_prep (x -> bf16 hi/lo planes) -> k_sq -> k_wt
//   -> k_knn single-pass: MFMA split-bf16 distances; index packed into low 12
//      mantissa bits; values-only med3 top-20/lane; 4-way merge -> top-24;
//      exact fp32 recheck -> top-20 set
//   -> k_res (residual x@Wres+bres via MFMA, pre-fills out)
//   -> k_edge (gather + MFMA MLP1 + LN + MFMA MLP2 + LN + max, adds into out)

#define NB 8
#define NPTS 4096
#define KNN 20
#define CIN 64
#define COUT 128
#define NTOT (NB * NPTS)       // 32768
#define NEDGE (NTOT * KNN)     // 655360
#define LDA 136                // bf16 row stride (128 + 8 pad) -> 272 B

typedef short bf16x8 __attribute__((ext_vector_type(8)));
typedef float f32x4 __attribute__((ext_vector_type(4)));

__device__ __forceinline__ unsigned short f2bf(float f) {
    union { float f; unsigned u; } v; v.f = f;
    unsigned r = v.u + 0x7FFFu + ((v.u >> 16) & 1u);   // RTNE
    return (unsigned short)(r >> 16);
}
__device__ __forceinline__ float bf2f(unsigned short s) {
    union { unsigned u; float f; } v; v.u = ((unsigned)s) << 16;
    return v.f;
}

// ---------------- x -> bf16 hi/lo planes ----------------
__global__ __launch_bounds__(256) void k_prep(const float* __restrict__ x,
                                              unsigned short* __restrict__ xhi,
                                              unsigned short* __restrict__ xlo) {
    int id = blockIdx.x * 2048 + threadIdx.x * 8;
    float4 v0 = *(const float4*)(x + id);
    float4 v1 = *(const float4*)(x + id + 4);
    float vs[8] = {v0.x, v0.y, v0.z, v0.w, v1.x, v1.y, v1.z, v1.w};
    unsigned short h[8], l[8];
#pragma unroll
    for (int i = 0; i < 8; ++i) {
        h[i] = f2bf(vs[i]);
        l[i] = f2bf(vs[i] - bf2f(h[i]));
    }
    uint4 hp, lp;
    hp.x = h[0] | ((unsigned)h[1] << 16); hp.y = h[2] | ((unsigned)h[3] << 16);
    hp.z = h[4] | ((unsigned)h[5] << 16); hp.w = h[6] | ((unsigned)h[7] << 16);
    lp.x = l[0] | ((unsigned)l[1] << 16); lp.y = l[2] | ((unsigned)l[3] << 16);
    lp.z = l[4] | ((unsigned)l[5] << 16); lp.w = l[6] | ((unsigned)l[7] << 16);
    *(uint4*)(xhi + id) = hp;
    *(uint4*)(xlo + id) = lp;
}

// ---------------- sq[n] = sum_c x[n][c]^2 ----------------
__global__ __launch_bounds__(256) void k_sq(const float* __restrict__ x, float* __restrict__ sq) {
    int t = threadIdx.x;
    int n = blockIdx.x * 4 + (t >> 6);
    int lane = t & 63;
    float v = x[n * 64 + lane];
    float s = v * v;
#pragma unroll
    for (int m = 32; m >= 1; m >>= 1) s += __shfl_xor(s, m);
    if (lane == 0) sq[n] = s;
}

// ---------------- transpose W1,W2,Wres -> bf16 [out][in] ----------------
__global__ __launch_bounds__(256) void k_wt(const float* __restrict__ W1, const float* __restrict__ W2,
                                            const float* __restrict__ Wres,
                                            unsigned short* __restrict__ w1t, unsigned short* __restrict__ w2t,
                                            unsigned short* __restrict__ wrt) {
    int id = blockIdx.x * 256 + threadIdx.x;   // 0..40959
    if (id < 16384) {
        int c = id >> 7, d = id & 127;
        w1t[d * 128 + c] = f2bf(W1[id]);
    } else if (id < 32768) {
        int i2 = id - 16384;
        int c = i2 >> 7, d = i2 & 127;
        w2t[d * 128 + c] = f2bf(W2[i2]);
    } else {
        int i3 = id - 32768;                   // Wres is [64][128]
        int c = i3 >> 7, d = i3 & 127;
        wrt[d * 64 + c] = f2bf(Wres[i3]);
    }
}

// ---------------- KNN via MFMA, single-pass packed ----------------
// Block: 256 thr = 4 waves; wave wv owns queries n0 + wv*16 + (lane&15).
// Lane owns (query lr, candidate quarter kg): streams 1024 of 4096 candidates.
// score packed as (bits & ~0xFFF) | idx12  -> med3 sorted insert carries the
// index for free (fmin/fmax are bit-preserving); values globally distinct.
// Merge 4 sorted lists -> top-24 packed; exact fp32 recheck -> top-20 set.
__global__ __launch_bounds__(256, 2) void k_knn(const float* __restrict__ x,
                                                const unsigned short* __restrict__ xhi,
                                                const unsigned short* __restrict__ xlo,
                                                const float* __restrict__ sq,
                                                int* __restrict__ knn_idx) {
    int b  = blockIdx.x & 7;           // cloud -> XCD pinning
    int qb = blockIdx.x >> 3;          // 0..63
    int t  = threadIdx.x;
    int wv = t >> 6, lane = t & 63;
    int lr = lane & 15, kg = lane >> 4;
    int n0  = b * NPTS + qb * 64;
    int cb0 = b * NPTS;

    __shared__ union {
        unsigned short frag[2][8][512];   // double-buffered A-fragments (16384 B)
        float ce[64][24];                 // exact recheck scores (epilogue)
    } F;
    __shared__ float md[64][81];          // per-lane sorted packed top-20 (20736 B)
    __shared__ float xq[64][68];          // fp32 query cache (17408 B)
    __shared__ int   ci[64][24];          // survivor candidate ids (6144 B)

    // query B-fragments (col = lane&15, k-slice kg*8), hi/lo x 2 K-halves
    int qg = n0 + wv * 16 + lr;
    bf16x8 qhi0 = *(const bf16x8*)(xhi + (size_t)qg * 64 + kg * 8);
    bf16x8 qhi1 = *(const bf16x8*)(xhi + (size_t)qg * 64 + 32 + kg * 8);
    bf16x8 qlo0 = *(const bf16x8*)(xlo + (size_t)qg * 64 + kg * 8);
    bf16x8 qlo1 = *(const bf16x8*)(xlo + (size_t)qg * 64 + 32 + kg * 8);

    // wave's staging role: frags f0=2wv (K-half 0), f1=2wv+1 (K-half 1);
    // candidate sub-tile stt=wv>>1, plane hi (wv even) / lo (wv odd)
    int stt = wv >> 1;
    const unsigned short* plane = (wv & 1) ? xlo : xhi;
    int f0 = 2 * wv, f1 = 2 * wv + 1;

    float kd[KNN];
#pragma unroll
    for (int p = 0; p < KNN; ++p) kd[p] = 3.4e38f;
    int myq = wv * 16 + lr;

    // prologue: fill buf0 with tile 0; issue loads for tile 1
    {
        const unsigned short* sp = plane + (size_t)(cb0 + stt * 16 + lr) * 64 + kg * 8;
        uint4 p0 = *(const uint4*)sp;
        uint4 p1 = *(const uint4*)(sp + 32);
        *(uint4*)&F.frag[0][f0][lane * 8] = p0;
        *(uint4*)&F.frag[0][f1][lane * 8] = p1;
    }
    uint4 gA0, gA1;
    {
        const unsigned short* sp = plane + (size_t)(cb0 + 32 + stt * 16 + lr) * 64 + kg * 8;
        gA0 = *(const uint4*)sp;
        gA1 = *(const uint4*)(sp + 32);
    }
    float4 sqc0 = *(const float4*)&sq[cb0 + kg * 4];
    float4 sqc1 = *(const float4*)&sq[cb0 + 16 + kg * 4];
    __syncthreads();

#pragma unroll 1
    for (int it = 0; it < 128; ++it) {
        int cur = it & 1;
        if (it + 1 < 128) {                    // stage next tile into the other buffer
            *(uint4*)&F.frag[cur ^ 1][f0][lane * 8] = gA0;
            *(uint4*)&F.frag[cur ^ 1][f1][lane * 8] = gA1;
        }
        if (it + 2 < 128) {                    // issue loads 2 tiles ahead
            const unsigned short* sp = plane + (size_t)(cb0 + (it + 2) * 32 + stt * 16 + lr) * 64 + kg * 8;
            gA0 = *(const uint4*)sp;
            gA1 = *(const uint4*)(sp + 32);
        }
        float4 nx0, nx1;
        if (it + 1 < 128) {                    // prefetch next sq
            nx0 = *(const float4*)&sq[cb0 + (it + 1) * 32 + kg * 4];
            nx1 = *(const float4*)&sq[cb0 + (it + 1) * 32 + 16 + kg * 4];
        }

        bf16x8 A0 = *(const bf16x8*)&F.frag[cur][0][lane * 8];
        bf16x8 A1 = *(const bf16x8*)&F.frag[cur][1][lane * 8];
        bf16x8 A2 = *(const bf16x8*)&F.frag[cur][2][lane * 8];
        bf16x8 A3 = *(const bf16x8*)&F.frag[cur][3][lane * 8];
        bf16x8 A4 = *(const bf16x8*)&F.frag[cur][4][lane * 8];
        bf16x8 A5 = *(const bf16x8*)&F.frag[cur][5][lane * 8];
        bf16x8 A6 = *(const bf16x8*)&F.frag[cur][6][lane * 8];
        bf16x8 A7 = *(const bf16x8*)&F.frag[cur][7][lane * 8];

        f32x4 a00 = {-0.5f * sqc0.x, -0.5f * sqc0.y, -0.5f * sqc0.z, -0.5f * sqc0.w};
        f32x4 a01 = {0.f, 0.f, 0.f, 0.f};
        f32x4 a10 = {-0.5f * sqc1.x, -0.5f * sqc1.y, -0.5f * sqc1.z, -0.5f * sqc1.w};
        f32x4 a11 = {0.f, 0.f, 0.f, 0.f};
        a00 = __builtin_amdgcn_mfma_f32_16x16x32_bf16(A0, qhi0, a00, 0, 0, 0);
        a10 = __builtin_amdgcn_mfma_f32_16x16x32_bf16(A4, qhi0, a10, 0, 0, 0);
        a01 = __builtin_amdgcn_mfma_f32_16x16x32_bf16(A1, qhi1, a01, 0, 0, 0);
        a11 = __builtin_amdgcn_mfma_f32_16x16x32_bf16(A5, qhi1, a11, 0, 0, 0);
        a00 = __builtin_amdgcn_mfma_f32_16x16x32_bf16(A2, qhi0, a00, 0, 0, 0);
        a10 = __builtin_amdgcn_mfma_f32_16x16x32_bf16(A6, qhi0, a10, 0, 0, 0);
        a01 = __builtin_amdgcn_mfma_f32_16x16x32_bf16(A3, qhi1, a01, 0, 0, 0);
        a11 = __builtin_amdgcn_mfma_f32_16x16x32_bf16(A7, qhi1, a11, 0, 0, 0);
        a00 = __builtin_amdgcn_mfma_f32_16x16x32_bf16(A0, qlo0, a00, 0, 0, 0);
        a10 = __builtin_amdgcn_mfma_f32_16x16x32_bf16(A4, qlo0, a10, 0, 0, 0);
        a01 = __builtin_amdgcn_mfma_f32_16x16x32_bf16(A1, qlo1, a01, 0, 0, 0);
        a11 = __builtin_amdgcn_mfma_f32_16x16x32_bf16(A5, qlo1, a11, 0, 0, 0);

        // pack (score | idx12) and unconditional med3 sorted insert (values only)
        int ibase = it * 32 + kg * 4;
#pragma unroll
        for (int j = 0; j < 8; ++j) {
            float sc = (j < 4) ? -(a00[j & 3] + a01[j & 3]) : -(a10[j & 3] + a11[j & 3]);
            unsigned idx12 = (unsigned)(ibase + ((j >> 2) << 4) + (j & 3));
            float xv = __uint_as_float((__float_as_uint(sc) & 0xFFFFF000u) | idx12);
#pragma unroll
            for (int p = KNN - 1; p >= 1; --p)
                kd[p] = fminf(fmaxf(xv, kd[p - 1]), kd[p]);
            kd[0] = fminf(kd[0], xv);
        }

        __syncthreads();                       // buf[cur^1] visible; buf[cur] free to overwrite
        sqc0 = nx0; sqc1 = nx1;
    }

    // publish per-lane sorted packed lists
#pragma unroll
    for (int p = 0; p < KNN; ++p) md[myq][kg * KNN + p] = kd[p];
    __syncthreads();

    // merge 4 sorted lists -> top-24 packed (t<64) || stage xq fp32 (t>=64; separate LDS)
    if (t < 64) {
        float kdm[24];
#pragma unroll
        for (int s = 0; s < 24; ++s) kdm[s] = 3.4e38f;
        float km = 3.4e38f;
#pragma unroll 1
        for (int u = 0; u < 4; ++u) {
#pragma unroll 1
            for (int p = 0; p < KNN; ++p) {
                float d = md[t][u * KNN + p];
                if (d >= km) break;            // ascending list: rest can't qualify
#pragma unroll
                for (int s = 23; s >= 1; --s)
                    kdm[s] = fminf(fmaxf(d, kdm[s - 1]), kdm[s]);
                kdm[0] = fminf(kdm[0], d);
                km = kdm[23];
            }
        }
#pragma unroll
        for (int s = 0; s < 24; ++s)
            ci[t][s] = (int)(__float_as_uint(kdm[s]) & 0xFFFu) + cb0;
    } else {
        for (int idx = t - 64; idx < 1024; idx += 192) {
            int q = idx >> 4, dg = idx & 15;
            *(float4*)&xq[q][dg * 4] = *(const float4*)(x + (size_t)(n0 + q) * 64 + dg * 4);
        }
    }
    __syncthreads();   // frag loop long done; F reused as ce below

    // exact fp32 recheck: 4 threads/query x 6 survivors
    {
        int q = t >> 2, sl = (t & 3) * 6;
#pragma unroll 1
        for (int u = 0; u < 6; ++u) {
            int cidx = ci[q][sl + u];
            const float* xc = x + (size_t)cidx * 64;
            float dot = 0.f;
#pragma unroll
            for (int g = 0; g < 16; ++g) {
                float4 a = *(const float4*)&xq[q][g * 4];
                float4 bb = *(const float4*)(xc + g * 4);
                dot += a.x * bb.x + a.y * bb.y + a.z * bb.z + a.w * bb.w;
            }
            F.ce[q][sl + u] = 0.5f * sq[cidx] - dot;
        }
    }
    __syncthreads();

    // exclude the 4 lexicographically-largest (score, then higher idx) -> exact top-20 set
    if (t < 64) {
        float ev[24]; int iv[24];
#pragma unroll
        for (int s = 0; s < 24; ++s) { ev[s] = F.ce[t][s]; iv[s] = ci[t][s]; }
        unsigned mask = 0;
#pragma unroll
        for (int pass = 0; pass < 4; ++pass) {
            float best = -3.4e38f; int bid = -1, bs = 0;
#pragma unroll
            for (int s = 0; s < 24; ++s) {
                bool free_ = ((mask >> s) & 1u) == 0u;
                bool gt = (ev[s] > best) || (ev[s] == best && iv[s] > bid);
                if (free_ && gt) { best = ev[s]; bid = iv[s]; bs = s; }
            }
            mask |= 1u << bs;
        }
        int* op = knn_idx + (size_t)(n0 + t) * KNN;
        int pos = 0;
#pragma unroll
        for (int s = 0; s < 24; ++s)
            if (((mask >> s) & 1u) == 0u) op[pos++] = iv[s];
    }
}

// ---------------- residual: out = x @ Wres + bres (MFMA) ----------------
__global__ __launch_bounds__(256) void k_res(const float* __restrict__ x,
                                             const unsigned short* __restrict__ wrt,
                                             const float* __restrict__ bres,
                                             float* __restrict__ out) {
    int t = threadIdx.x;
    int wv = t >> 6, lane = t & 63;
    int lr = lane & 15, kg = lane >> 4;
    int n0 = blockIdx.x * 64 + wv * 16;

    const float* xp = x + (size_t)(n0 + lr) * 64;
    bf16x8 af0, af1;
    {
        union { unsigned short u[8]; bf16x8 v; } cv;
        float4 u0 = *(const float4*)(xp + kg * 8);
        float4 u1 = *(const float4*)(xp + kg * 8 + 4);
        cv.u[0] = f2bf(u0.x); cv.u[1] = f2bf(u0.y); cv.u[2] = f2bf(u0.z); cv.u[3] = f2bf(u0.w);
        cv.u[4] = f2bf(u1.x); cv.u[5] = f2bf(u1.y); cv.u[6] = f2bf(u1.z); cv.u[7] = f2bf(u1.w);
        af0 = cv.v;
        float4 w0 = *(const float4*)(xp + 32 + kg * 8);
        float4 w1 = *(const float4*)(xp + 32 + kg * 8 + 4);
        cv.u[0] = f2bf(w0.x); cv.u[1] = f2bf(w0.y); cv.u[2] = f2bf(w0.z); cv.u[3] = f2bf(w0.w);
        cv.u[4] = f2bf(w1.x); cv.u[5] = f2bf(w1.y); cv.u[6] = f2bf(w1.z); cv.u[7] = f2bf(w1.w);
        af1 = cv.v;
    }
    f32x4 acc[8];
#pragma unroll
    for (int nt = 0; nt < 8; ++nt) {
        float bv = bres[nt * 16 + lr];
        acc[nt] = (f32x4){bv, bv, bv, bv};
    }
#pragma unroll
    for (int nt = 0; nt < 8; ++nt) {
        bf16x8 b0 = *(const bf16x8*)(wrt + (size_t)(nt * 16 + lr) * 64 + kg * 8);
        bf16x8 b1 = *(const bf16x8*)(wrt + (size_t)(nt * 16 + lr) * 64 + 32 + kg * 8);
        acc[nt] = __builtin_amdgcn_mfma_f32_16x16x32_bf16(af0, b0, acc[nt], 0, 0, 0);
        acc[nt] = __builtin_amdgcn_mfma_f32_16x16x32_bf16(af1, b1, acc[nt], 0, 0, 0);
    }
#pragma unroll
    for (int nt = 0; nt < 8; ++nt)
#pragma unroll
        for (int j = 0; j < 4; ++j)
            out[(size_t)(n0 + kg * 4 + j) * 128 + nt * 16 + lr] = acc[nt][j];
}

// ---------------- fused edge MLP ----------------
__device__ __forceinline__ void gemm_tile(const unsigned short* A, const unsigned short* Bw,
                                          int wv, int lane, f32x4 acc[2][8]) {
    int lr = lane & 15, kg = lane >> 4;
#pragma unroll
    for (int ks = 0; ks < 4; ++ks) {
        int ko = ks * 32 + kg * 8;
        bf16x8 a0 = *(const bf16x8*)(A + (size_t)(wv * 32 + lr) * LDA + ko);
        bf16x8 a1 = *(const bf16x8*)(A + (size_t)(wv * 32 + 16 + lr) * LDA + ko);
#pragma unroll
        for (int nt = 0; nt < 8; ++nt) {
            bf16x8 bf = *(const bf16x8*)(Bw + (size_t)(nt * 16 + lr) * LDA + ko);
            acc[0][nt] = __builtin_amdgcn_mfma_f32_16x16x32_bf16(a0, bf, acc[0][nt], 0, 0, 0);
            acc[1][nt] = __builtin_amdgcn_mfma_f32_16x16x32_bf16(a1, bf, acc[1][nt], 0, 0, 0);
        }
    }
}

__device__ __forceinline__ void ln_relu_store(f32x4 acc[2][8], unsigned short* A, int wv, int lane,
                                              const float* __restrict__ bias, const float* __restrict__ g,
                                              const float* __restrict__ be) {
    int lc = lane & 15, kg = lane >> 4;
    float bv[8], gv[8], bev[8];
#pragma unroll
    for (int nt = 0; nt < 8; ++nt) {
        bv[nt]  = bias[nt * 16 + lc];
        gv[nt]  = g[nt * 16 + lc];
        bev[nt] = be[nt * 16 + lc];
    }
#pragma unroll
    for (int mt = 0; mt < 2; ++mt) {
#pragma unroll
        for (int j = 0; j < 4; ++j) {
            float v[8]; float s = 0.f, ss = 0.f;
#pragma unroll
            for (int nt = 0; nt < 8; ++nt) {
                v[nt] = acc[mt][nt][j] + bv[nt];
                s += v[nt]; ss += v[nt] * v[nt];
            }
#pragma unroll
            for (int m = 1; m < 16; m <<= 1) { s += __shfl_xor(s, m); ss += __shfl_xor(ss, m); }
            float mean = s * 0.0078125f;
            float var  = ss * 0.0078125f - mean * mean;
            float rstd = rsqrtf(fmaxf(var, 0.f) + 1e-5f);
            int row = wv * 32 + mt * 16 + kg * 4 + j;
#pragma unroll
            for (int nt = 0; nt < 8; ++nt) {
                float h = (v[nt] - mean) * rstd * gv[nt] + bev[nt];
                h = fmaxf(h, 0.f);
                A[(size_t)row * LDA + nt * 16 + lc] = f2bf(h);
            }
        }
    }
}

__global__ __launch_bounds__(320) void k_edge(const float* __restrict__ x, const int* __restrict__ knn_idx,
                                              const unsigned short* __restrict__ w1t, const unsigned short* __restrict__ w2t,
                                              const float* __restrict__ b1, const float* __restrict__ g1, const float* __restrict__ be1,
                                              const float* __restrict__ b2, const float* __restrict__ g2, const float* __restrict__ be2,
                                              float* __restrict__ out) {
    __shared__ unsigned short A[160 * LDA];
    __shared__ unsigned short Bw[128 * LDA];
    int t = threadIdx.x;
    int blk = blockIdx.x;

    {
        int r = t >> 1, half = t & 1;
        int eg = blk * 160 + r;
        int n = eg / 20;
        int j = knn_idx[eg];
        const float* xi = x + (size_t)n * 64;
        if (half == 0) {
#pragma unroll
            for (int i = 0; i < 16; ++i) {
                float4 v = *(const float4*)(xi + i * 4);
                ushort4 pk; pk.x = f2bf(v.x); pk.y = f2bf(v.y); pk.z = f2bf(v.z); pk.w = f2bf(v.w);
                *(ushort4*)&A[(size_t)r * LDA + i * 4] = pk;
            }
        } else {
            const float* xj = x + (size_t)j * 64;
#pragma unroll
            for (int i = 0; i < 16; ++i) {
                float4 vi = *(const float4*)(xi + i * 4);
                float4 vj = *(const float4*)(xj + i * 4);
                ushort4 pk; pk.x = f2bf(vj.x - vi.x); pk.y = f2bf(vj.y - vi.y);
                pk.z = f2bf(vj.z - vi.z); pk.w = f2bf(vj.w - vi.w);
                *(ushort4*)&A[(size_t)r * LDA + 64 + i * 4] = pk;
            }
        }
    }
    for (int id = t; id < 2048; id += 320) {
        int row = id >> 4, ch = id & 15;
        *(uint4*)&Bw[(size_t)row * LDA + ch * 8] = *(const uint4*)(w1t + (size_t)row * 128 + ch * 8);
    }
    __syncthreads();

    int wv = t >> 6, lane = t & 63;
    f32x4 acc[2][8];
#pragma unroll
    for (int i = 0; i < 2; ++i)
#pragma unroll
        for (int j = 0; j < 8; ++j) acc[i][j] = (f32x4){0.f, 0.f, 0.f, 0.f};
    gemm_tile(A, Bw, wv, lane, acc);
    ln_relu_store(acc, A, wv, lane, b1, g1, be1);
    __syncthreads();
    for (int id = t; id < 2048; id += 320) {
        int row = id >> 4, ch = id & 15;
        *(uint4*)&Bw[(size_t)row * LDA + ch * 8] = *(const uint4*)(w2t + (size_t)row * 128 + ch * 8);
    }
    __syncthreads();

    f32x4 acc2[2][8];
#pragma unroll
    for (int i = 0; i < 2; ++i)
#pragma unroll
        for (int j = 0; j < 8; ++j) acc2[i][j] = (f32x4){0.f, 0.f, 0.f, 0.f};
    gemm_tile(A, Bw, wv, lane, acc2);
    ln_relu_store(acc2, A, wv, lane, b2, g2, be2);
    __syncthreads();

    // max over K, add into pre-filled residual
    for (int i = t; i < 1024; i += 320) {
        int p = i >> 7, c = i & 127;
        float mx = 0.f;
#pragma unroll
        for (int r = 0; r < 20; ++r)
            mx = fmaxf(mx, bf2f(A[(size_t)(p * 20 + r) * LDA + c]));
        int n = blk * 8 + p;
        out[(size_t)n * 128 + c] += mx;
    }
}

// ---------------- launcher ----------------
extern "C" void kernel_launch(void* const* d_in, const int* in_sizes, int n_in,
                              void* d_out, int out_size, void* d_ws, size_t ws_size,
                              hipStream_t stream) {
    const float* x    = (const float*)d_in[0];
    const float* W1   = (const float*)d_in[2];
    const float* b1   = (const float*)d_in[3];
    const float* g1   = (const float*)d_in[4];
    const float* be1  = (const float*)d_in[5];
    const float* W2   = (const float*)d_in[6];
    const float* b2   = (const float*)d_in[7];
    const float* g2   = (const float*)d_in[8];
    const float* be2  = (const float*)d_in[9];
    const float* Wres = (const float*)d_in[10];
    const float* bres = (const float*)d_in[11];
    float* out = (float*)d_out;

    char* ws = (char*)d_ws;
    float* sq            = (float*)(ws);                     // 131072 B
    unsigned short* w1t  = (unsigned short*)(ws + 131072);   // 32768 B
    unsigned short* w2t  = (unsigned short*)(ws + 163840);   // 32768 B
    int* knn_idx         = (int*)(ws + 196608);              // 2621440 B
    unsigned short* wrt  = (unsigned short*)(ws + 2818048);  // 16384 B  (total ~2.9 MB)

    // bf16 hi/lo planes staged inside d_out; consumed by k_knn, then overwritten by k_res
    unsigned short* xhi = (unsigned short*)d_out;                       // 4 MB
    unsigned short* xlo = (unsigned short*)((char*)d_out + 4194304);    // 4 MB

    k_prep <<<dim3(1024),     dim3(256), 0, stream>>>(x, xhi, xlo);
    k_sq   <<<dim3(NTOT / 4), dim3(256), 0, stream>>>(x, sq);
    k_wt   <<<dim3(160),      dim3(256), 0, stream>>>(W1, W2, Wres, w1t, w2t, wrt);
    k_knn  <<<dim3(NB * 64),  dim3(256), 0, stream>>>(x, xhi, xlo, sq, knn_idx);
    k_res  <<<dim3(NTOT / 64),dim3(256), 0, stream>>>(x, wrt, bres, out);
    k_edge <<<dim3(NEDGE / 160), dim3(320), 0, stream>>>(x, knn_idx, w1t, w2t,
                                                         b1, g1, be1, b2, g2, be2, out);
}

// Round 8
// 435.954 us; speedup vs baseline: 2.3523x; 1.3009x over previous
//
#include <hip/hip_runtime.h>
#include <hip/hip_bf16.h>

// EdgeConv block: B=8 clouds, N=4096 pts, K=20 nn, C_IN=64, C_OUT=128.
// Pipeline: k_prep (x -> bf16 hi/lo planes + sq) -> k_wt
//   -> k_knn (512-thr: 8 waves = 4 query-groups x 2 tile-parities; MFMA split-bf16
//      distances; idx packed in low 12 mantissa bits; med3 sorted top-20/lane;
//      8-way merge -> top-24; exact fp32 recheck -> top-20 set)
//   -> k_res (residual x@Wres+bres via MFMA, pre-fills out)
//   -> k_edge (gather + MFMA MLP1 + LN + MFMA MLP2 + LN + max, adds into out)

#define NB 8
#define NPTS 4096
#define KNN 20
#define CIN 64
#define COUT 128
#define NTOT (NB * NPTS)       // 32768
#define NEDGE (NTOT * KNN)     // 655360
#define LDA 136                // bf16 row stride (128 + 8 pad) -> 272 B

typedef short bf16x8 __attribute__((ext_vector_type(8)));
typedef float f32x4 __attribute__((ext_vector_type(4)));

__device__ __forceinline__ unsigned short f2bf(float f) {
    union { float f; unsigned u; } v; v.f = f;
    unsigned r = v.u + 0x7FFFu + ((v.u >> 16) & 1u);   // RTNE
    return (unsigned short)(r >> 16);
}
__device__ __forceinline__ float bf2f(unsigned short s) {
    union { unsigned u; float f; } v; v.u = ((unsigned)s) << 16;
    return v.f;
}

// ---------------- x -> bf16 hi/lo planes + row sq ----------------
__global__ __launch_bounds__(256) void k_prep(const float* __restrict__ x,
                                              unsigned short* __restrict__ xhi,
                                              unsigned short* __restrict__ xlo,
                                              float* __restrict__ sq) {
    int id = blockIdx.x * 2048 + threadIdx.x * 8;
    float4 v0 = *(const float4*)(x + id);
    float4 v1 = *(const float4*)(x + id + 4);
    float vs[8] = {v0.x, v0.y, v0.z, v0.w, v1.x, v1.y, v1.z, v1.w};
    unsigned short h[8], l[8];
    float s = 0.f;
#pragma unroll
    for (int i = 0; i < 8; ++i) {
        h[i] = f2bf(vs[i]);
        l[i] = f2bf(vs[i] - bf2f(h[i]));
        s += vs[i] * vs[i];
    }
    uint4 hp, lp;
    hp.x = h[0] | ((unsigned)h[1] << 16); hp.y = h[2] | ((unsigned)h[3] << 16);
    hp.z = h[4] | ((unsigned)h[5] << 16); hp.w = h[6] | ((unsigned)h[7] << 16);
    lp.x = l[0] | ((unsigned)l[1] << 16); lp.y = l[2] | ((unsigned)l[3] << 16);
    lp.z = l[4] | ((unsigned)l[5] << 16); lp.w = l[6] | ((unsigned)l[7] << 16);
    *(uint4*)(xhi + id) = hp;
    *(uint4*)(xlo + id) = lp;
    // 8 threads per 64-dim row: tree-reduce
    s += __shfl_xor(s, 1); s += __shfl_xor(s, 2); s += __shfl_xor(s, 4);
    if ((threadIdx.x & 7) == 0) sq[id >> 6] = s;
}

// ---------------- transpose W1,W2,Wres -> bf16 [out][in] ----------------
__global__ __launch_bounds__(256) void k_wt(const float* __restrict__ W1, const float* __restrict__ W2,
                                            const float* __restrict__ Wres,
                                            unsigned short* __restrict__ w1t, unsigned short* __restrict__ w2t,
                                            unsigned short* __restrict__ wrt) {
    int id = blockIdx.x * 256 + threadIdx.x;   // 0..40959
    if (id < 16384) {
        int c = id >> 7, d = id & 127;
        w1t[d * 128 + c] = f2bf(W1[id]);
    } else if (id < 32768) {
        int i2 = id - 16384;
        int c = i2 >> 7, d = i2 & 127;
        w2t[d * 128 + c] = f2bf(W2[i2]);
    } else {
        int i3 = id - 32768;                   // Wres is [64][128]
        int c = i3 >> 7, d = i3 & 127;
        wrt[d * 64 + c] = f2bf(Wres[i3]);
    }
}

// ---------------- KNN via MFMA, 8-wave single-pass ----------------
// Block: 512 thr = 8 waves = 4 query-groups (w>>1) x 2 tile-parities (w&1).
// Super-iteration s covers tiles 2s (even waves) and 2s+1 (odd waves), 32 cands each.
// Lane = (query lr, cand quarter kg) streams 512 pairs; score packed with idx12;
// insert = 19 med3 + 1 min (branchless, depth 2). Staging: wave w stages frag w of
// both tiles (2 uint4/thread), 2-super register prefetch, 1 barrier/super.
__global__ __launch_bounds__(512, 4) void k_knn(const float* __restrict__ x,
                                                const unsigned short* __restrict__ xhi,
                                                const unsigned short* __restrict__ xlo,
                                                const float* __restrict__ sq,
                                                int* __restrict__ knn_idx) {
    int b  = blockIdx.x & 7;           // cloud -> XCD pinning
    int qb = blockIdx.x >> 3;          // 0..63
    int t  = threadIdx.x;
    int w = t >> 6, lane = t & 63;
    int lr = lane & 15, kg = lane >> 4;
    int qgrp = w >> 1, tp = w & 1;
    int n0  = b * NPTS + qb * 64;
    int cb0 = b * NPTS;

    __shared__ union {
        unsigned short ring[2][2][8][512];                        // 32768 B: [pair][tilepar][f][shorts]
        struct { int ci[64][24]; int pad_[512]; float ce[64][24]; } e;
    } R;
    __shared__ float md[64][161];                                 // 41216 B: 8 sorted lists x 20 per query

    // B-frags: this wave's query group
    int qg = n0 + qgrp * 16 + lr;
    bf16x8 qhi0 = *(const bf16x8*)(xhi + (size_t)qg * 64 + kg * 8);
    bf16x8 qhi1 = *(const bf16x8*)(xhi + (size_t)qg * 64 + 32 + kg * 8);
    bf16x8 qlo0 = *(const bf16x8*)(xlo + (size_t)qg * 64 + kg * 8);
    bf16x8 qlo1 = *(const bf16x8*)(xlo + (size_t)qg * 64 + 32 + kg * 8);

    // staging role: wave w stages frag f=w of both tiles: tt=w>>2, plane=(w>>1)&1, kh=w&1
    const unsigned short* splane = ((w >> 1) & 1) ? xlo : xhi;
    int stt = w >> 2, skh = w & 1;
    // per-lane source offset within a tile: row = tile*32 + stt*16 + (lane&15), k = skh*32 + (lane>>4)*8
    size_t soff = (size_t)(stt * 16 + (lane & 15)) * 64 + skh * 32 + (lane >> 4) * 8;

    float kd[KNN];
#pragma unroll
    for (int p = 0; p < KNN; ++p) kd[p] = 3.4e38f;
    int myq = qgrp * 16 + lr;

    // prologue: stage super 0 (tiles 0,1); prefetch super 1 (tiles 2,3)
    {
        uint4 p0 = *(const uint4*)(splane + (size_t)cb0 * 64 + soff);              // tile 0
        uint4 p1 = *(const uint4*)(splane + (size_t)(cb0 + 32) * 64 + soff);       // tile 1
        *(uint4*)&R.ring[0][0][w][lane * 8] = p0;
        *(uint4*)&R.ring[0][1][w][lane * 8] = p1;
    }
    uint4 g0 = *(const uint4*)(splane + (size_t)(cb0 + 64) * 64 + soff);           // tile 2
    uint4 g1 = *(const uint4*)(splane + (size_t)(cb0 + 96) * 64 + soff);           // tile 3
    float4 sqc0 = *(const float4*)&sq[cb0 + tp * 32 + kg * 4];
    float4 sqc1 = *(const float4*)&sq[cb0 + tp * 32 + 16 + kg * 4];
    __syncthreads();

#pragma unroll 1
    for (int s = 0; s < 64; ++s) {
        if (s + 1 < 64) {                      // publish prefetched super s+1
            *(uint4*)&R.ring[(s + 1) & 1][0][w][lane * 8] = g0;
            *(uint4*)&R.ring[(s + 1) & 1][1][w][lane * 8] = g1;
        }
        if (s + 2 < 64) {                      // issue loads for super s+2
            g0 = *(const uint4*)(splane + (size_t)(cb0 + (2 * s + 4) * 32) * 64 + soff);
            g1 = *(const uint4*)(splane + (size_t)(cb0 + (2 * s + 5) * 32) * 64 + soff);
        }
        float4 nsq0, nsq1;
        if (s + 1 < 64) {
            nsq0 = *(const float4*)&sq[cb0 + (2 * (s + 1) + tp) * 32 + kg * 4];
            nsq1 = *(const float4*)&sq[cb0 + (2 * (s + 1) + tp) * 32 + 16 + kg * 4];
        }

        const unsigned short* fr = &R.ring[s & 1][tp][0][0];
        bf16x8 A0 = *(const bf16x8*)(fr + 0 * 512 + lane * 8);
        bf16x8 A1 = *(const bf16x8*)(fr + 1 * 512 + lane * 8);
        bf16x8 A2 = *(const bf16x8*)(fr + 2 * 512 + lane * 8);
        bf16x8 A3 = *(const bf16x8*)(fr + 3 * 512 + lane * 8);
        bf16x8 A4 = *(const bf16x8*)(fr + 4 * 512 + lane * 8);
        bf16x8 A5 = *(const bf16x8*)(fr + 5 * 512 + lane * 8);
        bf16x8 A6 = *(const bf16x8*)(fr + 6 * 512 + lane * 8);
        bf16x8 A7 = *(const bf16x8*)(fr + 7 * 512 + lane * 8);

        f32x4 a00 = {-0.5f * sqc0.x, -0.5f * sqc0.y, -0.5f * sqc0.z, -0.5f * sqc0.w};
        f32x4 a01 = {0.f, 0.f, 0.f, 0.f};
        f32x4 a10 = {-0.5f * sqc1.x, -0.5f * sqc1.y, -0.5f * sqc1.z, -0.5f * sqc1.w};
        f32x4 a11 = {0.f, 0.f, 0.f, 0.f};
        a00 = __builtin_amdgcn_mfma_f32_16x16x32_bf16(A0, qhi0, a00, 0, 0, 0);
        a10 = __builtin_amdgcn_mfma_f32_16x16x32_bf16(A4, qhi0, a10, 0, 0, 0);
        a01 = __builtin_amdgcn_mfma_f32_16x16x32_bf16(A1, qhi1, a01, 0, 0, 0);
        a11 = __builtin_amdgcn_mfma_f32_16x16x32_bf16(A5, qhi1, a11, 0, 0, 0);
        a00 = __builtin_amdgcn_mfma_f32_16x16x32_bf16(A2, qhi0, a00, 0, 0, 0);
        a10 = __builtin_amdgcn_mfma_f32_16x16x32_bf16(A6, qhi0, a10, 0, 0, 0);
        a01 = __builtin_amdgcn_mfma_f32_16x16x32_bf16(A3, qhi1, a01, 0, 0, 0);
        a11 = __builtin_amdgcn_mfma_f32_16x16x32_bf16(A7, qhi1, a11, 0, 0, 0);
        a00 = __builtin_amdgcn_mfma_f32_16x16x32_bf16(A0, qlo0, a00, 0, 0, 0);
        a10 = __builtin_amdgcn_mfma_f32_16x16x32_bf16(A4, qlo0, a10, 0, 0, 0);
        a01 = __builtin_amdgcn_mfma_f32_16x16x32_bf16(A1, qlo1, a01, 0, 0, 0);
        a11 = __builtin_amdgcn_mfma_f32_16x16x32_bf16(A5, qlo1, a11, 0, 0, 0);

        // pack (score | idx12) and med3 sorted insert (19 med3 + 1 min per pair)
        int ibase = (2 * s + tp) * 32 + kg * 4;
#pragma unroll
        for (int j = 0; j < 8; ++j) {
            float sc = (j < 4) ? -(a00[j & 3] + a01[j & 3]) : -(a10[j & 3] + a11[j & 3]);
            unsigned idx12 = (unsigned)(ibase + ((j >> 2) << 4) + (j & 3));
            float xv = __uint_as_float((__float_as_uint(sc) & 0xFFFFF000u) | idx12);
#pragma unroll
            for (int p = KNN - 1; p >= 1; --p)
                kd[p] = __builtin_amdgcn_fmed3f(xv, kd[p - 1], kd[p]);
            kd[0] = fminf(kd[0], xv);
        }

        __syncthreads();                       // super s+1 visible; pair s&1 safe to overwrite next iter
        sqc0 = nsq0; sqc1 = nsq1;
    }

    // publish per-lane sorted packed lists: slot = tp*4 + kg
#pragma unroll
    for (int p = 0; p < KNN; ++p) md[myq][(tp * 4 + kg) * KNN + p] = kd[p];
    __syncthreads();

    // merge 8 sorted lists -> top-24 packed (t<64); ring dead -> ci/ce overlay
    if (t < 64) {
        float kdm[24];
#pragma unroll
        for (int s2 = 0; s2 < 24; ++s2) kdm[s2] = 3.4e38f;
        float km = 3.4e38f;
#pragma unroll 1
        for (int u = 0; u < 8; ++u) {
#pragma unroll 1
            for (int p = 0; p < KNN; ++p) {
                float d = md[t][u * KNN + p];
                if (d >= km) break;            // ascending list: rest can't qualify
#pragma unroll
                for (int s2 = 23; s2 >= 1; --s2)
                    kdm[s2] = __builtin_amdgcn_fmed3f(d, kdm[s2 - 1], kdm[s2]);
                kdm[0] = fminf(kdm[0], d);
                km = kdm[23];
            }
        }
#pragma unroll
        for (int s2 = 0; s2 < 24; ++s2)
            R.e.ci[t][s2] = (int)(__float_as_uint(kdm[s2]) & 0xFFFu) + cb0;
    }
    __syncthreads();

    // exact fp32 recheck: 1536 tasks over 512 threads (query rows L1-hot from global)
#pragma unroll 1
    for (int task = t; task < 1536; task += 512) {
        int q = task / 24, sl = task - q * 24;
        int cidx = R.e.ci[q][sl];
        const float* xqp = x + (size_t)(n0 + q) * 64;
        const float* xc  = x + (size_t)cidx * 64;
        float dot = 0.f;
#pragma unroll
        for (int g = 0; g < 16; ++g) {
            float4 a = *(const float4*)(xqp + g * 4);
            float4 bb = *(const float4*)(xc + g * 4);
            dot += a.x * bb.x + a.y * bb.y + a.z * bb.z + a.w * bb.w;
        }
        R.e.ce[q][sl] = 0.5f * sq[cidx] - dot;
    }
    __syncthreads();

    // exclude the 4 lexicographically-largest (score, then higher idx) -> exact top-20 set
    if (t < 64) {
        float ev[24]; int iv[24];
#pragma unroll
        for (int s2 = 0; s2 < 24; ++s2) { ev[s2] = R.e.ce[t][s2]; iv[s2] = R.e.ci[t][s2]; }
        unsigned mask = 0;
#pragma unroll
        for (int pass = 0; pass < 4; ++pass) {
            float best = -3.4e38f; int bid = -1, bs = 0;
#pragma unroll
            for (int s2 = 0; s2 < 24; ++s2) {
                bool free_ = ((mask >> s2) & 1u) == 0u;
                bool gt = (ev[s2] > best) || (ev[s2] == best && iv[s2] > bid);
                if (free_ && gt) { best = ev[s2]; bid = iv[s2]; bs = s2; }
            }
            mask |= 1u << bs;
        }
        int* op = knn_idx + (size_t)(n0 + t) * KNN;
        int pos = 0;
#pragma unroll
        for (int s2 = 0; s2 < 24; ++s2)
            if (((mask >> s2) & 1u) == 0u) op[pos++] = iv[s2];
    }
}

// ---------------- residual: out = x @ Wres + bres (MFMA) ----------------
__global__ __launch_bounds__(256) void k_res(const float* __restrict__ x,
                                             const unsigned short* __restrict__ wrt,
                                             const float* __restrict__ bres,
                                             float* __restrict__ out) {
    int t = threadIdx.x;
    int wv = t >> 6, lane = t & 63;
    int lr = lane & 15, kg = lane >> 4;
    int n0 = blockIdx.x * 64 + wv * 16;

    const float* xp = x + (size_t)(n0 + lr) * 64;
    bf16x8 af0, af1;
    {
        union { unsigned short u[8]; bf16x8 v; } cv;
        float4 u0 = *(const float4*)(xp + kg * 8);
        float4 u1 = *(const float4*)(xp + kg * 8 + 4);
        cv.u[0] = f2bf(u0.x); cv.u[1] = f2bf(u0.y); cv.u[2] = f2bf(u0.z); cv.u[3] = f2bf(u0.w);
        cv.u[4] = f2bf(u1.x); cv.u[5] = f2bf(u1.y); cv.u[6] = f2bf(u1.z); cv.u[7] = f2bf(u1.w);
        af0 = cv.v;
        float4 w0 = *(const float4*)(xp + 32 + kg * 8);
        float4 w1 = *(const float4*)(xp + 32 + kg * 8 + 4);
        cv.u[0] = f2bf(w0.x); cv.u[1] = f2bf(w0.y); cv.u[2] = f2bf(w0.z); cv.u[3] = f2bf(w0.w);
        cv.u[4] = f2bf(w1.x); cv.u[5] = f2bf(w1.y); cv.u[6] = f2bf(w1.z); cv.u[7] = f2bf(w1.w);
        af1 = cv.v;
    }
    f32x4 acc[8];
#pragma unroll
    for (int nt = 0; nt < 8; ++nt) {
        float bv = bres[nt * 16 + lr];
        acc[nt] = (f32x4){bv, bv, bv, bv};
    }
#pragma unroll
    for (int nt = 0; nt < 8; ++nt) {
        bf16x8 b0 = *(const bf16x8*)(wrt + (size_t)(nt * 16 + lr) * 64 + kg * 8);
        bf16x8 b1 = *(const bf16x8*)(wrt + (size_t)(nt * 16 + lr) * 64 + 32 + kg * 8);
        acc[nt] = __builtin_amdgcn_mfma_f32_16x16x32_bf16(af0, b0, acc[nt], 0, 0, 0);
        acc[nt] = __builtin_amdgcn_mfma_f32_16x16x32_bf16(af1, b1, acc[nt], 0, 0, 0);
    }
#pragma unroll
    for (int nt = 0; nt < 8; ++nt)
#pragma unroll
        for (int j = 0; j < 4; ++j)
            out[(size_t)(n0 + kg * 4 + j) * 128 + nt * 16 + lr] = acc[nt][j];
}

// ---------------- fused edge MLP ----------------
__device__ __forceinline__ void gemm_tile(const unsigned short* A, const unsigned short* Bw,
                                          int wv, int lane, f32x4 acc[2][8]) {
    int lr = lane & 15, kg = lane >> 4;
#pragma unroll
    for (int ks = 0; ks < 4; ++ks) {
        int ko = ks * 32 + kg * 8;
        bf16x8 a0 = *(const bf16x8*)(A + (size_t)(wv * 32 + lr) * LDA + ko);
        bf16x8 a1 = *(const bf16x8*)(A + (size_t)(wv * 32 + 16 + lr) * LDA + ko);
#pragma unroll
        for (int nt = 0; nt < 8; ++nt) {
            bf16x8 bf = *(const bf16x8*)(Bw + (size_t)(nt * 16 + lr) * LDA + ko);
            acc[0][nt] = __builtin_amdgcn_mfma_f32_16x16x32_bf16(a0, bf, acc[0][nt], 0, 0, 0);
            acc[1][nt] = __builtin_amdgcn_mfma_f32_16x16x32_bf16(a1, bf, acc[1][nt], 0, 0, 0);
        }
    }
}

__device__ __forceinline__ void ln_relu_store(f32x4 acc[2][8], unsigned short* A, int wv, int lane,
                                              const float* __restrict__ bias, const float* __restrict__ g,
                                              const float* __restrict__ be) {
    int lc = lane & 15, kg = lane >> 4;
    float bv[8], gv[8], bev[8];
#pragma unroll
    for (int nt = 0; nt < 8; ++nt) {
        bv[nt]  = bias[nt * 16 + lc];
        gv[nt]  = g[nt * 16 + lc];
        bev[nt] = be[nt * 16 + lc];
    }
#pragma unroll
    for (int mt = 0; mt < 2; ++mt) {
#pragma unroll
        for (int j = 0; j < 4; ++j) {
            float v[8]; float s = 0.f, ss = 0.f;
#pragma unroll
            for (int nt = 0; nt < 8; ++nt) {
                v[nt] = acc[mt][nt][j] + bv[nt];
                s += v[nt]; ss += v[nt] * v[nt];
            }
#pragma unroll
            for (int m = 1; m < 16; m <<= 1) { s += __shfl_xor(s, m); ss += __shfl_xor(ss, m); }
            float mean = s * 0.0078125f;
            float var  = ss * 0.0078125f - mean * mean;
            float rstd = rsqrtf(fmaxf(var, 0.f) + 1e-5f);
            int row = wv * 32 + mt * 16 + kg * 4 + j;
#pragma unroll
            for (int nt = 0; nt < 8; ++nt) {
                float h = (v[nt] - mean) * rstd * gv[nt] + bev[nt];
                h = fmaxf(h, 0.f);
                A[(size_t)row * LDA + nt * 16 + lc] = f2bf(h);
            }
        }
    }
}

__global__ __launch_bounds__(320) void k_edge(const float* __restrict__ x, const int* __restrict__ knn_idx,
                                              const unsigned short* __restrict__ w1t, const unsigned short* __restrict__ w2t,
                                              const float* __restrict__ b1, const float* __restrict__ g1, const float* __restrict__ be1,
                                              const float* __restrict__ b2, const float* __restrict__ g2, const float* __restrict__ be2,
                                              float* __restrict__ out) {
    __shared__ unsigned short A[160 * LDA];
    __shared__ unsigned short Bw[128 * LDA];
    int t = threadIdx.x;
    int blk = blockIdx.x;

    {
        int r = t >> 1, half = t & 1;
        int eg = blk * 160 + r;
        int n = eg / 20;
        int j = knn_idx[eg];
        const float* xi = x + (size_t)n * 64;
        if (half == 0) {
#pragma unroll
            for (int i = 0; i < 16; ++i) {
                float4 v = *(const float4*)(xi + i * 4);
                ushort4 pk; pk.x = f2bf(v.x); pk.y = f2bf(v.y); pk.z = f2bf(v.z); pk.w = f2bf(v.w);
                *(ushort4*)&A[(size_t)r * LDA + i * 4] = pk;
            }
        } else {
            const float* xj = x + (size_t)j * 64;
#pragma unroll
            for (int i = 0; i < 16; ++i) {
                float4 vi = *(const float4*)(xi + i * 4);
                float4 vj = *(const float4*)(xj + i * 4);
                ushort4 pk; pk.x = f2bf(vj.x - vi.x); pk.y = f2bf(vj.y - vi.y);
                pk.z = f2bf(vj.z - vi.z); pk.w = f2bf(vj.w - vi.w);
                *(ushort4*)&A[(size_t)r * LDA + 64 + i * 4] = pk;
            }
        }
    }
    for (int id = t; id < 2048; id += 320) {
        int row = id >> 4, ch = id & 15;
        *(uint4*)&Bw[(size_t)row * LDA + ch * 8] = *(const uint4*)(w1t + (size_t)row * 128 + ch * 8);
    }
    __syncthreads();

    int wv = t >> 6, lane = t & 63;
    f32x4 acc[2][8];
#pragma unroll
    for (int i = 0; i < 2; ++i)
#pragma unroll
        for (int j = 0; j < 8; ++j) acc[i][j] = (f32x4){0.f, 0.f, 0.f, 0.f};
    gemm_tile(A, Bw, wv, lane, acc);
    ln_relu_store(acc, A, wv, lane, b1, g1, be1);
    __syncthreads();
    for (int id = t; id < 2048; id += 320) {
        int row = id >> 4, ch = id & 15;
        *(uint4*)&Bw[(size_t)row * LDA + ch * 8] = *(const uint4*)(w2t + (size_t)row * 128 + ch * 8);
    }
    __syncthreads();

    f32x4 acc2[2][8];
#pragma unroll
    for (int i = 0; i < 2; ++i)
#pragma unroll
        for (int j = 0; j < 8; ++j) acc2[i][j] = (f32x4){0.f, 0.f, 0.f, 0.f};
    gemm_tile(A, Bw, wv, lane, acc2);
    ln_relu_store(acc2, A, wv, lane, b2, g2, be2);
    __syncthreads();

    // max over K (vectorized b128 row reads), add into pre-filled residual
    if (t < 128) {
        int p = t >> 4, cg = t & 15;
        int n = blk * 8 + p;
        float mx[8];
#pragma unroll
        for (int k = 0; k < 8; ++k) mx[k] = 0.f;    // relu outputs >= 0
#pragma unroll
        for (int r = 0; r < 20; ++r) {
            uint4 v = *(const uint4*)&A[(size_t)(p * 20 + r) * LDA + cg * 8];
            unsigned uu[4] = {v.x, v.y, v.z, v.w};
#pragma unroll
            for (int k = 0; k < 4; ++k) {
                float lo = __uint_as_float(uu[k] << 16);
                float hi = __uint_as_float(uu[k] & 0xFFFF0000u);
                mx[2 * k]     = fmaxf(mx[2 * k], lo);
                mx[2 * k + 1] = fmaxf(mx[2 * k + 1], hi);
            }
        }
        float* op = out + (size_t)n * 128 + cg * 8;
        float4 o0 = *(float4*)op;
        float4 o1 = *(float4*)(op + 4);
        o0.x += mx[0]; o0.y += mx[1]; o0.z += mx[2]; o0.w += mx[3];
        o1.x += mx[4]; o1.y += mx[5]; o1.z += mx[6]; o1.w += mx[7];
        *(float4*)op = o0;
        *(float4*)(op + 4) = o1;
    }
}

// ---------------- launcher ----------------
extern "C" void kernel_launch(void* const* d_in, const int* in_sizes, int n_in,
                              void* d_out, int out_size, void* d_ws, size_t ws_size,
                              hipStream_t stream) {
    const float* x    = (const float*)d_in[0];
    const float* W1   = (const float*)d_in[2];
    const float* b1   = (const float*)d_in[3];
    const float* g1   = (const float*)d_in[4];
    const float* be1  = (const float*)d_in[5];
    const float* W2   = (const float*)d_in[6];
    const float* b2   = (const float*)d_in[7];
    const float* g2   = (const float*)d_in[8];
    const float* be2  = (const float*)d_in[9];
    const float* Wres = (const float*)d_in[10];
    const float* bres = (const float*)d_in[11];
    float* out = (float*)d_out;

    char* ws = (char*)d_ws;
    float* sq            = (float*)(ws);                     // 131072 B
    unsigned short* w1t  = (unsigned short*)(ws + 131072);   // 32768 B
    unsigned short* w2t  = (unsigned short*)(ws + 163840);   // 32768 B
    int* knn_idx         = (int*)(ws + 196608);              // 2621440 B
    unsigned short* wrt  = (unsigned short*)(ws + 2818048);  // 16384 B  (total ~2.9 MB)

    // bf16 hi/lo planes staged inside d_out; consumed by k_knn, then overwritten by k_res
    unsigned short* xhi = (unsigned short*)d_out;                       // 4 MB
    unsigned short* xlo = (unsigned short*)((char*)d_out + 4194304);    // 4 MB

    k_prep <<<dim3(1024),      dim3(256), 0, stream>>>(x, xhi, xlo, sq);
    k_wt   <<<dim3(160),       dim3(256), 0, stream>>>(W1, W2, Wres, w1t, w2t, wrt);
    k_knn  <<<dim3(NB * 64),   dim3(512), 0, stream>>>(x, xhi, xlo, sq, knn_idx);
    k_res  <<<dim3(NTOT / 64), dim3(256), 0, stream>>>(x, wrt, bres, out);
    k_edge <<<dim3(NEDGE / 160), dim3(320), 0, stream>>>(x, knn_idx, w1t, w2t,
                                                         b1, g1, be1, b2, g2, be2, out);
}